// Round 2
// 479.220 us; speedup vs baseline: 1.0164x; 1.0164x over previous
//
#include <hip/hip_runtime.h>
#include <math.h>

// ---------------------------------------------------------------------------
// GAT 3-layer net. CSR by dst built once per call; per-layer:
//   gemm+al fused (h = X@W, al_s/al_d epilogue), agg (per-dst softmax+gather).
// R1: k_pool run-length accumulation (batch sorted) — 362us -> ~5us.
// R2: k_agg 3-pass with per-edge scratch (scratch e/exp).
// R3: hierarchical 3-kernel coalesced scan (was 76us single-block).
// R4: k_agg pass C quarter-wave-per-edge (float4x2 row gather, 8-edge
//     unroll => 2x in-flight lines, half the load instrs); k_al fused into
//     gemm epilogues; k_copy folded into k_scan3.
// R5: k_agg register-resident softmax for deg<=64 (one lane per edge,
//     shfl-xor reductions, alpha broadcast via shfl in pass C).
// R6: FIX R5 — shfls in the <4-edge tail were inside a divergent guard;
//     ds_bpermute from an exec-masked-off lane is UNDEFINED. Hoist shfls
//     out of the guard (uniform execution), guard only the gather.
// ---------------------------------------------------------------------------

__global__ __launch_bounds__(256) void k_count(const int* __restrict__ ei,
                                               int* __restrict__ cnt, int E, int N) {
  int i = blockIdx.x * 256 + threadIdx.x;
  int tot = E + N;
  if (i >= tot) return;
  int dst = (i < E) ? ei[E + i] : (i - E);
  atomicAdd(&cnt[dst], 1);
}

// hierarchical scan, stage 1: 1024 elems/block (256 thr x int4).
__global__ __launch_bounds__(256) void k_scan1(const int* __restrict__ cnt,
                                               int* __restrict__ rowp,
                                               int* __restrict__ bsum, int n) {
  __shared__ int sm[256];
  int tid = threadIdx.x;
  int base = blockIdx.x * 1024 + tid * 4;
  int4 v = {0, 0, 0, 0};
  if (base + 3 < n) v = *(const int4*)(cnt + base);
  else {
    if (base + 0 < n) v.x = cnt[base + 0];
    if (base + 1 < n) v.y = cnt[base + 1];
    if (base + 2 < n) v.z = cnt[base + 2];
    if (base + 3 < n) v.w = cnt[base + 3];
  }
  int s = v.x + v.y + v.z + v.w;
  sm[tid] = s;
  __syncthreads();
  for (int off = 1; off < 256; off <<= 1) {
    int t = (tid >= off) ? sm[tid - off] : 0;
    __syncthreads();
    sm[tid] += t;
    __syncthreads();
  }
  int pre = sm[tid] - s;
  int r0 = pre, r1 = pre + v.x, r2 = r1 + v.y, r3 = r2 + v.z;
  if (base + 3 < n) { int4 o = {r0, r1, r2, r3}; *(int4*)(rowp + base) = o; }
  else {
    if (base + 0 < n) rowp[base + 0] = r0;
    if (base + 1 < n) rowp[base + 1] = r1;
    if (base + 2 < n) rowp[base + 2] = r2;
    if (base + 3 < n) rowp[base + 3] = r3;
  }
  if (tid == 255) bsum[blockIdx.x] = sm[255];
}

// stage 2: single block exclusive-scans nb (<=256) block sums in place
__global__ __launch_bounds__(256) void k_scan2(int* __restrict__ bsum, int nb) {
  __shared__ int sm[256];
  int tid = threadIdx.x;
  int v = (tid < nb) ? bsum[tid] : 0;
  sm[tid] = v;
  __syncthreads();
  for (int off = 1; off < 256; off <<= 1) {
    int t = (tid >= off) ? sm[tid - off] : 0;
    __syncthreads();
    sm[tid] += t;
    __syncthreads();
  }
  if (tid < nb) bsum[tid] = sm[tid] - v;
}

// stage 3: add block offsets; write final rowp AND cursor copy; rowp[n]=total
__global__ __launch_bounds__(256) void k_scan3(int* __restrict__ rowp,
                                               int* __restrict__ cursor,
                                               const int* __restrict__ bsum,
                                               int n, int total) {
  int tid = threadIdx.x;
  int base = blockIdx.x * 1024 + tid * 4;
  int off = bsum[blockIdx.x];
  if (base + 3 < n) {
    int4 v = *(int4*)(rowp + base);
    v.x += off; v.y += off; v.z += off; v.w += off;
    *(int4*)(rowp + base) = v;
    *(int4*)(cursor + base) = v;
  } else {
    for (int i = 0; i < 4; ++i)
      if (base + i < n) { int t = rowp[base + i] + off; rowp[base + i] = t; cursor[base + i] = t; }
  }
  if (blockIdx.x == 0 && tid == 0) rowp[n] = total;
}

__global__ __launch_bounds__(256) void k_scatter(const int* __restrict__ ei,
                                                 int* __restrict__ cursor,
                                                 int* __restrict__ csr_src, int E, int N) {
  int i = blockIdx.x * 256 + threadIdx.x;
  int tot = E + N;
  if (i >= tot) return;
  int src, dst;
  if (i < E) { src = ei[i]; dst = ei[E + i]; }
  else       { src = i - E; dst = i - E; }
  int pos = atomicAdd(&cursor[dst], 1);
  csr_src[pos] = src;
}

// layer-1 GEMM fused with al: one wave per node, lane owns 2 features.
__global__ __launch_bounds__(256) void k_gemm4al(const float* __restrict__ X,
                                                 const float* __restrict__ W,
                                                 const float* __restrict__ asv,
                                                 const float* __restrict__ adv,
                                                 float* __restrict__ Hout,
                                                 float* __restrict__ al_s,
                                                 float* __restrict__ al_d, int N) {
  int wid = threadIdx.x >> 6, lane = threadIdx.x & 63;
  int node = blockIdx.x * 4 + wid;
  if (node >= N) return;
  float4 xv = *(const float4*)(X + node * 4);
  int f = lane * 2;
  float2 w0 = *(const float2*)(W + f);
  float2 w1 = *(const float2*)(W + 128 + f);
  float2 w2 = *(const float2*)(W + 256 + f);
  float2 w3 = *(const float2*)(W + 384 + f);
  float h0 = xv.x * w0.x + xv.y * w1.x + xv.z * w2.x + xv.w * w3.x;
  float h1 = xv.x * w0.y + xv.y * w1.y + xv.z * w2.y + xv.w * w3.y;
  float2 hv = {h0, h1};
  *(float2*)(Hout + node * 128 + f) = hv;
  float2 s2 = *(const float2*)(asv + f);
  float2 d2 = *(const float2*)(adv + f);
  float ps = h0 * s2.x + h1 * s2.y;
  float pd = h0 * d2.x + h1 * d2.y;
  for (int off = 32; off; off >>= 1) {
    ps += __shfl_xor(ps, off);
    pd += __shfl_xor(pd, off);
  }
  if (lane == 0) { al_s[node] = ps; al_d[node] = pd; }
}

// GEMM: X [N,128] @ W [128,128] -> Hout [N,128], fused al epilogue.
__global__ __launch_bounds__(256) void k_gemm128al(const float* __restrict__ X,
                                                   const float* __restrict__ W,
                                                   const float* __restrict__ asv,
                                                   const float* __restrict__ adv,
                                                   float* __restrict__ Hout,
                                                   float* __restrict__ al_s,
                                                   float* __restrict__ al_d, int N) {
  __shared__ float Ws[64 * 128];    // 32 KB
  __shared__ float Xs[64 * 68];     // 17 KB
  int tid = threadIdx.x;
  int base = blockIdx.x * 64;
  int ty = tid >> 4, tx = tid & 15;

  float acc[4][8];
#pragma unroll
  for (int r = 0; r < 4; ++r)
#pragma unroll
    for (int c = 0; c < 8; ++c) acc[r][c] = 0.f;

  for (int kk = 0; kk < 128; kk += 64) {
    __syncthreads();
    for (int i = tid * 4; i < 64 * 128; i += 1024) {
      *(float4*)(Ws + i) = *(const float4*)(W + kk * 128 + i);
    }
    for (int i = tid; i < 64 * 16; i += 256) {
      int node = i >> 4, k4 = (i & 15) << 2;
      int gn = base + node;
      float4 v;
      if (gn < N) v = *(const float4*)(X + gn * 128 + kk + k4);
      else        v = make_float4(0.f, 0.f, 0.f, 0.f);
      *(float4*)(Xs + node * 68 + k4) = v;
    }
    __syncthreads();

    for (int k = 0; k < 64; ++k) {
      float a0 = Xs[(ty * 4 + 0) * 68 + k];
      float a1 = Xs[(ty * 4 + 1) * 68 + k];
      float a2 = Xs[(ty * 4 + 2) * 68 + k];
      float a3 = Xs[(ty * 4 + 3) * 68 + k];
      float4 b0 = *(const float4*)(Ws + k * 128 + tx * 8);
      float4 b1 = *(const float4*)(Ws + k * 128 + tx * 8 + 4);
      acc[0][0] += a0 * b0.x; acc[0][1] += a0 * b0.y; acc[0][2] += a0 * b0.z; acc[0][3] += a0 * b0.w;
      acc[0][4] += a0 * b1.x; acc[0][5] += a0 * b1.y; acc[0][6] += a0 * b1.z; acc[0][7] += a0 * b1.w;
      acc[1][0] += a1 * b0.x; acc[1][1] += a1 * b0.y; acc[1][2] += a1 * b0.z; acc[1][3] += a1 * b0.w;
      acc[1][4] += a1 * b1.x; acc[1][5] += a1 * b1.y; acc[1][6] += a1 * b1.z; acc[1][7] += a1 * b1.w;
      acc[2][0] += a2 * b0.x; acc[2][1] += a2 * b0.y; acc[2][2] += a2 * b0.z; acc[2][3] += a2 * b0.w;
      acc[2][4] += a2 * b1.x; acc[2][5] += a2 * b1.y; acc[2][6] += a2 * b1.z; acc[2][7] += a2 * b1.w;
      acc[3][0] += a3 * b0.x; acc[3][1] += a3 * b0.y; acc[3][2] += a3 * b0.z; acc[3][3] += a3 * b0.w;
      acc[3][4] += a3 * b1.x; acc[3][5] += a3 * b1.y; acc[3][6] += a3 * b1.z; acc[3][7] += a3 * b1.w;
    }
  }

  // epilogue: store h and fused al reduction (tx-group of 16 lanes per row)
  float4 as0 = *(const float4*)(asv + tx * 8);
  float4 as1 = *(const float4*)(asv + tx * 8 + 4);
  float4 ad0 = *(const float4*)(adv + tx * 8);
  float4 ad1 = *(const float4*)(adv + tx * 8 + 4);
#pragma unroll
  for (int r = 0; r < 4; ++r) {
    int gn = base + ty * 4 + r;
    float ps = acc[r][0] * as0.x + acc[r][1] * as0.y + acc[r][2] * as0.z + acc[r][3] * as0.w
             + acc[r][4] * as1.x + acc[r][5] * as1.y + acc[r][6] * as1.z + acc[r][7] * as1.w;
    float pd = acc[r][0] * ad0.x + acc[r][1] * ad0.y + acc[r][2] * ad0.z + acc[r][3] * ad0.w
             + acc[r][4] * ad1.x + acc[r][5] * ad1.y + acc[r][6] * ad1.z + acc[r][7] * ad1.w;
    for (int off = 1; off < 16; off <<= 1) {
      ps += __shfl_xor(ps, off);
      pd += __shfl_xor(pd, off);
    }
    if (gn < N) {
      float4 o0 = make_float4(acc[r][0], acc[r][1], acc[r][2], acc[r][3]);
      float4 o1 = make_float4(acc[r][4], acc[r][5], acc[r][6], acc[r][7]);
      *(float4*)(Hout + gn * 128 + tx * 8) = o0;
      *(float4*)(Hout + gn * 128 + tx * 8 + 4) = o1;
      if (tx == 0) { al_s[gn] = ps; al_d[gn] = pd; }
    }
  }
}

// per-dst softmax + aggregation. one wave per dst.
// Fast path (deg <= 64, always true for this graph): lane owns one edge.
//   e/alpha live in registers; softmax via two 6-step shfl_xor reductions;
//   pass C reads src-id and alpha via __shfl broadcast (no scratch memory).
//   ALL shfls execute under uniform control flow (bpermute from an
//   exec-masked lane is undefined); only gathers are guarded.
// Fallback (deg > 64): original 3-pass per-edge scratch path through exw.
// Pass C: quarter-wave per edge: 16 lanes own the 512B row (float4 x2),
//         4 edges/wave-step, 8-edge unroll; cross-quarter shfl reduce.
__global__ __launch_bounds__(256) void k_agg(const int* __restrict__ csr_src,
                                             const int* __restrict__ rowp,
                                             const float* __restrict__ al_s,
                                             const float* __restrict__ al_d,
                                             const float* __restrict__ Hh,
                                             const float* __restrict__ bias,
                                             float* __restrict__ exw,
                                             float* __restrict__ Yout, int N, int relu) {
  int wid = threadIdx.x >> 6, lane = threadIdx.x & 63;
  int dst = blockIdx.x * 4 + wid;
  if (dst >= N) return;
  int beg = rowp[dst], end = rowp[dst + 1];
  int deg = end - beg;
  float ald = al_d[dst];

  int q = lane >> 4;       // quarter = edge offset within 4-edge group
  int l = lane & 15;       // feature lane: owns feats [l*8, l*8+8)
  const float* Hl = Hh + l * 8;
  float acc[8];
#pragma unroll
  for (int c = 0; c < 8; ++c) acc[c] = 0.f;

  if (deg <= 64) {
    // ---- register-resident softmax ----
    int srcv = 0;
    float e = -INFINITY;
    if (lane < deg) {
      srcv = csr_src[beg + lane];
      e = al_s[srcv] + ald;
      e = (e > 0.f) ? e : 0.2f * e;
    }
    float m = e;
    for (int off = 32; off; off >>= 1) m = fmaxf(m, __shfl_xor(m, off));
    float av = (lane < deg) ? __expf(e - m) : 0.f;
    float den = av;
    for (int off = 32; off; off >>= 1) den += __shfl_xor(den, off);
    av *= 1.0f / (den + 1e-16f);   // alpha, pre-normalized, in lane=edge

    int t = 0;
    for (; t + 8 <= deg; t += 8) {     // deg uniform: wave-uniform loop
      int sA = __shfl(srcv, t + q);
      int sB = __shfl(srcv, t + 4 + q);
      float wA = __shfl(av, t + q);
      float wB = __shfl(av, t + 4 + q);
      const float* rA = Hl + (size_t)sA * 128;
      const float* rB = Hl + (size_t)sB * 128;
      float4 a0 = *(const float4*)(rA);
      float4 a1 = *(const float4*)(rA + 4);
      float4 b0 = *(const float4*)(rB);
      float4 b1 = *(const float4*)(rB + 4);
      acc[0] += wA * a0.x + wB * b0.x;
      acc[1] += wA * a0.y + wB * b0.y;
      acc[2] += wA * a0.z + wB * b0.z;
      acc[3] += wA * a0.w + wB * b0.w;
      acc[4] += wA * a1.x + wB * b1.x;
      acc[5] += wA * a1.y + wB * b1.y;
      acc[6] += wA * a1.z + wB * b1.z;
      acc[7] += wA * a1.w + wB * b1.w;
    }
    if (t + 4 <= deg) {                // uniform guard
      int sA = __shfl(srcv, t + q);
      float wA = __shfl(av, t + q);
      const float* rA = Hl + (size_t)sA * 128;
      float4 a0 = *(const float4*)(rA);
      float4 a1 = *(const float4*)(rA + 4);
      acc[0] += wA * a0.x; acc[1] += wA * a0.y; acc[2] += wA * a0.z; acc[3] += wA * a0.w;
      acc[4] += wA * a1.x; acc[5] += wA * a1.y; acc[6] += wA * a1.z; acc[7] += wA * a1.w;
      t += 4;
    }
    {
      // tail: shfls hoisted OUT of the divergent guard (uniform exec);
      // selector t+q <= 63 always valid; unused pulls are discarded.
      int sA = __shfl(srcv, t + q);
      float wA = __shfl(av, t + q);
      if (t + q < deg) {               // divergent: memory ops only
        const float* rA = Hl + (size_t)sA * 128;
        float4 a0 = *(const float4*)(rA);
        float4 a1 = *(const float4*)(rA + 4);
        acc[0] += wA * a0.x; acc[1] += wA * a0.y; acc[2] += wA * a0.z; acc[3] += wA * a0.w;
        acc[4] += wA * a1.x; acc[5] += wA * a1.y; acc[6] += wA * a1.z; acc[7] += wA * a1.w;
      }
    }
  } else {
    // ---- generic fallback: 3-pass with per-edge scratch ----
    float m = -INFINITY;
    for (int j = beg + lane; j < end; j += 64) {
      float e = al_s[csr_src[j]] + ald;
      e = (e > 0.f) ? e : 0.2f * e;
      exw[j] = e;
      m = fmaxf(m, e);
    }
    for (int off = 32; off; off >>= 1) m = fmaxf(m, __shfl_xor(m, off));

    float den = 0.f;
    for (int j = beg + lane; j < end; j += 64) {
      float ex = __expf(exw[j] - m);
      exw[j] = ex;
      den += ex;
    }
    for (int off = 32; off; off >>= 1) den += __shfl_xor(den, off);
    float inv = 1.0f / (den + 1e-16f);

    int j = beg;
    for (; j + 8 <= end; j += 8) {
      int sA = csr_src[j + q];
      int sB = csr_src[j + 4 + q];
      float wA = exw[j + q] * inv;
      float wB = exw[j + 4 + q] * inv;
      const float* rA = Hl + (size_t)sA * 128;
      const float* rB = Hl + (size_t)sB * 128;
      float4 a0 = *(const float4*)(rA);
      float4 a1 = *(const float4*)(rA + 4);
      float4 b0 = *(const float4*)(rB);
      float4 b1 = *(const float4*)(rB + 4);
      acc[0] += wA * a0.x + wB * b0.x;
      acc[1] += wA * a0.y + wB * b0.y;
      acc[2] += wA * a0.z + wB * b0.z;
      acc[3] += wA * a0.w + wB * b0.w;
      acc[4] += wA * a1.x + wB * b1.x;
      acc[5] += wA * a1.y + wB * b1.y;
      acc[6] += wA * a1.z + wB * b1.z;
      acc[7] += wA * a1.w + wB * b1.w;
    }
    if (j + 4 <= end) {
      int sA = csr_src[j + q];
      float wA = exw[j + q] * inv;
      const float* rA = Hl + (size_t)sA * 128;
      float4 a0 = *(const float4*)(rA);
      float4 a1 = *(const float4*)(rA + 4);
      acc[0] += wA * a0.x; acc[1] += wA * a0.y; acc[2] += wA * a0.z; acc[3] += wA * a0.w;
      acc[4] += wA * a1.x; acc[5] += wA * a1.y; acc[6] += wA * a1.z; acc[7] += wA * a1.w;
      j += 4;
    }
    if (j + q < end) {
      int sA = csr_src[j + q];
      float wA = exw[j + q] * inv;
      const float* rA = Hl + (size_t)sA * 128;
      float4 a0 = *(const float4*)(rA);
      float4 a1 = *(const float4*)(rA + 4);
      acc[0] += wA * a0.x; acc[1] += wA * a0.y; acc[2] += wA * a0.z; acc[3] += wA * a0.w;
      acc[4] += wA * a1.x; acc[5] += wA * a1.y; acc[6] += wA * a1.z; acc[7] += wA * a1.w;
    }
  }

#pragma unroll
  for (int c = 0; c < 8; ++c) {
    acc[c] += __shfl_xor(acc[c], 16);
    acc[c] += __shfl_xor(acc[c], 32);
  }
  if (q == 0) {
    float4 bv0 = *(const float4*)(bias + l * 8);
    float4 bv1 = *(const float4*)(bias + l * 8 + 4);
    float4 o0 = make_float4(acc[0] + bv0.x, acc[1] + bv0.y, acc[2] + bv0.z, acc[3] + bv0.w);
    float4 o1 = make_float4(acc[4] + bv1.x, acc[5] + bv1.y, acc[6] + bv1.z, acc[7] + bv1.w);
    if (relu) {
      o0.x = fmaxf(o0.x, 0.f); o0.y = fmaxf(o0.y, 0.f); o0.z = fmaxf(o0.z, 0.f); o0.w = fmaxf(o0.w, 0.f);
      o1.x = fmaxf(o1.x, 0.f); o1.y = fmaxf(o1.y, 0.f); o1.z = fmaxf(o1.z, 0.f); o1.w = fmaxf(o1.w, 0.f);
    }
    *(float4*)(Yout + (size_t)dst * 128 + l * 8) = o0;
    *(float4*)(Yout + (size_t)dst * 128 + l * 8 + 4) = o1;
  }
}

// run-length pooling over sorted batch
__global__ __launch_bounds__(256) void k_pool(const float* __restrict__ Hh,
                                              const int* __restrict__ batch,
                                              float* __restrict__ gsum,
                                              float* __restrict__ gcnt,
                                              int N, int nwaves) {
  int gw = (blockIdx.x * 256 + threadIdx.x) >> 6;
  int lane = threadIdx.x & 63;
  int chunk = (N + nwaves - 1) / nwaves;
  int beg = gw * chunk;
  int end = beg + chunk; if (end > N) end = N;
  if (beg >= end) return;

  int curg = batch[beg];
  float2 acc = {0.f, 0.f};
  int cnt = 0;
  for (int n = beg; n < end; ++n) {
    int g = batch[n];
    if (g != curg) {
      atomicAdd(&gsum[curg * 128 + lane * 2], acc.x);
      atomicAdd(&gsum[curg * 128 + lane * 2 + 1], acc.y);
      if (lane == 0) atomicAdd(&gcnt[curg], (float)cnt);
      acc.x = 0.f; acc.y = 0.f; cnt = 0; curg = g;
    }
    float2 h = *(const float2*)(Hh + (size_t)n * 128 + lane * 2);
    acc.x += h.x; acc.y += h.y; ++cnt;
  }
  atomicAdd(&gsum[curg * 128 + lane * 2], acc.x);
  atomicAdd(&gsum[curg * 128 + lane * 2 + 1], acc.y);
  if (lane == 0) atomicAdd(&gcnt[curg], (float)cnt);
}

__global__ __launch_bounds__(128) void k_final(const float* __restrict__ gsum,
                                               const float* __restrict__ gcnt,
                                               const float* __restrict__ Wlin,
                                               const float* __restrict__ blin,
                                               float* __restrict__ out) {
  int t = threadIdx.x;  // 128 threads: (g, c) pairs
  int g = t >> 1, c = t & 1;
  float inv = 1.0f / fmaxf(gcnt[g], 1.0f);
  float acc = blin[c];
  for (int k = 0; k < 128; ++k) acc += gsum[g * 128 + k] * inv * Wlin[k * 2 + c];
  out[g * 2 + c] = acc;
}

extern "C" void kernel_launch(void* const* d_in, const int* in_sizes, int n_in,
                              void* d_out, int out_size, void* d_ws, size_t ws_size,
                              hipStream_t stream) {
  const float* x    = (const float*)d_in[0];
  const int*   ei   = (const int*)d_in[1];
  const int*   batch= (const int*)d_in[2];
  const float* W1   = (const float*)d_in[3];
  const float* as1  = (const float*)d_in[4];
  const float* ad1  = (const float*)d_in[5];
  const float* b1   = (const float*)d_in[6];
  const float* W2   = (const float*)d_in[7];
  const float* as2  = (const float*)d_in[8];
  const float* ad2  = (const float*)d_in[9];
  const float* b2   = (const float*)d_in[10];
  const float* W3   = (const float*)d_in[11];
  const float* as3  = (const float*)d_in[12];
  const float* ad3  = (const float*)d_in[13];
  const float* b3   = (const float*)d_in[14];
  const float* Wlin = (const float*)d_in[15];
  const float* blin = (const float*)d_in[16];

  int N = in_sizes[0] / 4;
  int E = in_sizes[1] / 2;
  int ET = E + N;

  char* ws = (char*)d_ws;
  float* bufA = (float*)ws; ws += (size_t)N * 128 * 4;
  float* bufB = (float*)ws; ws += (size_t)N * 128 * 4;
  float* al_s = (float*)ws; ws += (size_t)N * 4;
  float* al_d = (float*)ws; ws += (size_t)N * 4;
  float* gsum = (float*)ws; ws += (size_t)64 * 128 * 4;
  float* gcnt = (float*)ws; ws += (size_t)64 * 4;
  int* rowp   = (int*)ws;   ws += (size_t)(N + 1) * 4;
  int* cursor = (int*)ws;   ws += (size_t)N * 4;
  int* csr    = (int*)ws;   ws += (size_t)ET * 4;
  float* exw  = (float*)ws; ws += (size_t)ET * 4;
  int* bsum   = (int*)ws;   ws += (size_t)256 * 4;

  hipMemsetAsync(cursor, 0, (size_t)N * 4, stream);
  hipMemsetAsync(gsum, 0, (size_t)(64 * 128 + 64) * 4, stream);  // gsum + gcnt

  int eb = (ET + 255) / 256;
  int nsb = (N + 1023) / 1024;  // scan blocks (<=256)
  k_count  <<<eb, 256, 0, stream>>>(ei, cursor, E, N);
  k_scan1  <<<nsb, 256, 0, stream>>>(cursor, rowp, bsum, N);
  k_scan2  <<<1, 256, 0, stream>>>(bsum, nsb);
  k_scan3  <<<nsb, 256, 0, stream>>>(rowp, cursor, bsum, N, ET);
  k_scatter<<<eb, 256, 0, stream>>>(ei, cursor, csr, E, N);

  int nb4 = (N + 3) / 4;
  // layer 1
  k_gemm4al<<<nb4, 256, 0, stream>>>(x, W1, as1, ad1, bufA, al_s, al_d, N);
  k_agg    <<<nb4, 256, 0, stream>>>(csr, rowp, al_s, al_d, bufA, b1, exw, bufB, N, 1);
  // layer 2
  k_gemm128al<<<(N + 63) / 64, 256, 0, stream>>>(bufB, W2, as2, ad2, bufA, al_s, al_d, N);
  k_agg      <<<nb4, 256, 0, stream>>>(csr, rowp, al_s, al_d, bufA, b2, exw, bufB, N, 1);
  // layer 3
  k_gemm128al<<<(N + 63) / 64, 256, 0, stream>>>(bufB, W3, as3, ad3, bufA, al_s, al_d, N);
  k_agg      <<<nb4, 256, 0, stream>>>(csr, rowp, al_s, al_d, bufA, b3, exw, bufB, N, 0);

  // global mean pool + linear head (256 blocks x 4 waves = 1024 waves)
  k_pool <<<256, 256, 0, stream>>>(bufB, batch, gsum, gcnt, N, 1024);
  k_final<<<1, 128, 0, stream>>>(gsum, gcnt, Wlin, blin, (float*)d_out);
}

// Round 3
// 421.908 us; speedup vs baseline: 1.1545x; 1.1358x over previous
//
#include <hip/hip_runtime.h>
#include <math.h>

// ---------------------------------------------------------------------------
// GAT 3-layer net. CSR by dst built once per call; per-layer:
//   gemm+al fused (h = X@W, al_s/al_d epilogue), agg (per-dst softmax+gather).
// R1: k_pool run-length accumulation (batch sorted) — 362us -> ~5us.
// R2: k_agg 3-pass with per-edge scratch (scratch e/exp).
// R3: hierarchical 3-kernel coalesced scan (was 76us single-block).
// R4: k_agg pass C quarter-wave-per-edge; k_al fused into gemm epilogues.
// R5: k_agg register-resident softmax for deg<=64 (lane-per-edge, shfl).
// R6: FIX R5 — shfls hoisted out of divergent tail guard (bpermute from
//     exec-masked lane is undefined).
// R7: bf16 gather table. GEMM epilogues emit a packed-bf16 copy of H
//     (RNE); k_agg fast path gathers 16B/lane/edge (one uint4, 8 bf16)
//     instead of 32B — halves gather traffic AND the L2 working set
//     (25.6 -> 12.8 MB). Softmax/accum/al stay f32. Fallback stays f32.
// ---------------------------------------------------------------------------

__device__ __forceinline__ float bflo(unsigned u) { return __uint_as_float(u << 16); }
__device__ __forceinline__ float bfhi(unsigned u) { return __uint_as_float(u & 0xffff0000u); }
// pack two f32 -> two bf16 (round-nearest-even), a in low half, b in high
__device__ __forceinline__ unsigned pk2bf(float a, float b) {
  unsigned ua = __float_as_uint(a); ua += 0x7fffu + ((ua >> 16) & 1u);
  unsigned ub = __float_as_uint(b); ub += 0x7fffu + ((ub >> 16) & 1u);
  return (ua >> 16) | (ub & 0xffff0000u);
}

__global__ __launch_bounds__(256) void k_count(const int* __restrict__ ei,
                                               int* __restrict__ cnt, int E, int N) {
  int i = blockIdx.x * 256 + threadIdx.x;
  int tot = E + N;
  if (i >= tot) return;
  int dst = (i < E) ? ei[E + i] : (i - E);
  atomicAdd(&cnt[dst], 1);
}

// hierarchical scan, stage 1: 1024 elems/block (256 thr x int4).
__global__ __launch_bounds__(256) void k_scan1(const int* __restrict__ cnt,
                                               int* __restrict__ rowp,
                                               int* __restrict__ bsum, int n) {
  __shared__ int sm[256];
  int tid = threadIdx.x;
  int base = blockIdx.x * 1024 + tid * 4;
  int4 v = {0, 0, 0, 0};
  if (base + 3 < n) v = *(const int4*)(cnt + base);
  else {
    if (base + 0 < n) v.x = cnt[base + 0];
    if (base + 1 < n) v.y = cnt[base + 1];
    if (base + 2 < n) v.z = cnt[base + 2];
    if (base + 3 < n) v.w = cnt[base + 3];
  }
  int s = v.x + v.y + v.z + v.w;
  sm[tid] = s;
  __syncthreads();
  for (int off = 1; off < 256; off <<= 1) {
    int t = (tid >= off) ? sm[tid - off] : 0;
    __syncthreads();
    sm[tid] += t;
    __syncthreads();
  }
  int pre = sm[tid] - s;
  int r0 = pre, r1 = pre + v.x, r2 = r1 + v.y, r3 = r2 + v.z;
  if (base + 3 < n) { int4 o = {r0, r1, r2, r3}; *(int4*)(rowp + base) = o; }
  else {
    if (base + 0 < n) rowp[base + 0] = r0;
    if (base + 1 < n) rowp[base + 1] = r1;
    if (base + 2 < n) rowp[base + 2] = r2;
    if (base + 3 < n) rowp[base + 3] = r3;
  }
  if (tid == 255) bsum[blockIdx.x] = sm[255];
}

// stage 2: single block exclusive-scans nb (<=256) block sums in place
__global__ __launch_bounds__(256) void k_scan2(int* __restrict__ bsum, int nb) {
  __shared__ int sm[256];
  int tid = threadIdx.x;
  int v = (tid < nb) ? bsum[tid] : 0;
  sm[tid] = v;
  __syncthreads();
  for (int off = 1; off < 256; off <<= 1) {
    int t = (tid >= off) ? sm[tid - off] : 0;
    __syncthreads();
    sm[tid] += t;
    __syncthreads();
  }
  if (tid < nb) bsum[tid] = sm[tid] - v;
}

// stage 3: add block offsets; write final rowp AND cursor copy; rowp[n]=total
__global__ __launch_bounds__(256) void k_scan3(int* __restrict__ rowp,
                                               int* __restrict__ cursor,
                                               const int* __restrict__ bsum,
                                               int n, int total) {
  int tid = threadIdx.x;
  int base = blockIdx.x * 1024 + tid * 4;
  int off = bsum[blockIdx.x];
  if (base + 3 < n) {
    int4 v = *(int4*)(rowp + base);
    v.x += off; v.y += off; v.z += off; v.w += off;
    *(int4*)(rowp + base) = v;
    *(int4*)(cursor + base) = v;
  } else {
    for (int i = 0; i < 4; ++i)
      if (base + i < n) { int t = rowp[base + i] + off; rowp[base + i] = t; cursor[base + i] = t; }
  }
  if (blockIdx.x == 0 && tid == 0) rowp[n] = total;
}

__global__ __launch_bounds__(256) void k_scatter(const int* __restrict__ ei,
                                                 int* __restrict__ cursor,
                                                 int* __restrict__ csr_src, int E, int N) {
  int i = blockIdx.x * 256 + threadIdx.x;
  int tot = E + N;
  if (i >= tot) return;
  int src, dst;
  if (i < E) { src = ei[i]; dst = ei[E + i]; }
  else       { src = i - E; dst = i - E; }
  int pos = atomicAdd(&cursor[dst], 1);
  csr_src[pos] = src;
}

// layer-1 GEMM fused with al: one wave per node, lane owns 2 features.
__global__ __launch_bounds__(256) void k_gemm4al(const float* __restrict__ X,
                                                 const float* __restrict__ W,
                                                 const float* __restrict__ asv,
                                                 const float* __restrict__ adv,
                                                 float* __restrict__ Hout,
                                                 unsigned* __restrict__ Hbf,
                                                 float* __restrict__ al_s,
                                                 float* __restrict__ al_d, int N) {
  int wid = threadIdx.x >> 6, lane = threadIdx.x & 63;
  int node = blockIdx.x * 4 + wid;
  if (node >= N) return;
  float4 xv = *(const float4*)(X + node * 4);
  int f = lane * 2;
  float2 w0 = *(const float2*)(W + f);
  float2 w1 = *(const float2*)(W + 128 + f);
  float2 w2 = *(const float2*)(W + 256 + f);
  float2 w3 = *(const float2*)(W + 384 + f);
  float h0 = xv.x * w0.x + xv.y * w1.x + xv.z * w2.x + xv.w * w3.x;
  float h1 = xv.x * w0.y + xv.y * w1.y + xv.z * w2.y + xv.w * w3.y;
  float2 hv = {h0, h1};
  *(float2*)(Hout + node * 128 + f) = hv;
  Hbf[node * 64 + lane] = pk2bf(h0, h1);
  float2 s2 = *(const float2*)(asv + f);
  float2 d2 = *(const float2*)(adv + f);
  float ps = h0 * s2.x + h1 * s2.y;
  float pd = h0 * d2.x + h1 * d2.y;
  for (int off = 32; off; off >>= 1) {
    ps += __shfl_xor(ps, off);
    pd += __shfl_xor(pd, off);
  }
  if (lane == 0) { al_s[node] = ps; al_d[node] = pd; }
}

// GEMM: X [N,128] @ W [128,128] -> Hout [N,128] (+bf16 copy), fused al epilogue.
__global__ __launch_bounds__(256) void k_gemm128al(const float* __restrict__ X,
                                                   const float* __restrict__ W,
                                                   const float* __restrict__ asv,
                                                   const float* __restrict__ adv,
                                                   float* __restrict__ Hout,
                                                   uint4* __restrict__ Hbf,
                                                   float* __restrict__ al_s,
                                                   float* __restrict__ al_d, int N) {
  __shared__ float Ws[64 * 128];    // 32 KB
  __shared__ float Xs[64 * 68];     // 17 KB
  int tid = threadIdx.x;
  int base = blockIdx.x * 64;
  int ty = tid >> 4, tx = tid & 15;

  float acc[4][8];
#pragma unroll
  for (int r = 0; r < 4; ++r)
#pragma unroll
    for (int c = 0; c < 8; ++c) acc[r][c] = 0.f;

  for (int kk = 0; kk < 128; kk += 64) {
    __syncthreads();
    for (int i = tid * 4; i < 64 * 128; i += 1024) {
      *(float4*)(Ws + i) = *(const float4*)(W + kk * 128 + i);
    }
    for (int i = tid; i < 64 * 16; i += 256) {
      int node = i >> 4, k4 = (i & 15) << 2;
      int gn = base + node;
      float4 v;
      if (gn < N) v = *(const float4*)(X + gn * 128 + kk + k4);
      else        v = make_float4(0.f, 0.f, 0.f, 0.f);
      *(float4*)(Xs + node * 68 + k4) = v;
    }
    __syncthreads();

    for (int k = 0; k < 64; ++k) {
      float a0 = Xs[(ty * 4 + 0) * 68 + k];
      float a1 = Xs[(ty * 4 + 1) * 68 + k];
      float a2 = Xs[(ty * 4 + 2) * 68 + k];
      float a3 = Xs[(ty * 4 + 3) * 68 + k];
      float4 b0 = *(const float4*)(Ws + k * 128 + tx * 8);
      float4 b1 = *(const float4*)(Ws + k * 128 + tx * 8 + 4);
      acc[0][0] += a0 * b0.x; acc[0][1] += a0 * b0.y; acc[0][2] += a0 * b0.z; acc[0][3] += a0 * b0.w;
      acc[0][4] += a0 * b1.x; acc[0][5] += a0 * b1.y; acc[0][6] += a0 * b1.z; acc[0][7] += a0 * b1.w;
      acc[1][0] += a1 * b0.x; acc[1][1] += a1 * b0.y; acc[1][2] += a1 * b0.z; acc[1][3] += a1 * b0.w;
      acc[1][4] += a1 * b1.x; acc[1][5] += a1 * b1.y; acc[1][6] += a1 * b1.z; acc[1][7] += a1 * b1.w;
      acc[2][0] += a2 * b0.x; acc[2][1] += a2 * b0.y; acc[2][2] += a2 * b0.z; acc[2][3] += a2 * b0.w;
      acc[2][4] += a2 * b1.x; acc[2][5] += a2 * b1.y; acc[2][6] += a2 * b1.z; acc[2][7] += a2 * b1.w;
      acc[3][0] += a3 * b0.x; acc[3][1] += a3 * b0.y; acc[3][2] += a3 * b0.z; acc[3][3] += a3 * b0.w;
      acc[3][4] += a3 * b1.x; acc[3][5] += a3 * b1.y; acc[3][6] += a3 * b1.z; acc[3][7] += a3 * b1.w;
    }
  }

  // epilogue: store h (f32 + bf16) and fused al reduction
  float4 as0 = *(const float4*)(asv + tx * 8);
  float4 as1 = *(const float4*)(asv + tx * 8 + 4);
  float4 ad0 = *(const float4*)(adv + tx * 8);
  float4 ad1 = *(const float4*)(adv + tx * 8 + 4);
#pragma unroll
  for (int r = 0; r < 4; ++r) {
    int gn = base + ty * 4 + r;
    float ps = acc[r][0] * as0.x + acc[r][1] * as0.y + acc[r][2] * as0.z + acc[r][3] * as0.w
             + acc[r][4] * as1.x + acc[r][5] * as1.y + acc[r][6] * as1.z + acc[r][7] * as1.w;
    float pd = acc[r][0] * ad0.x + acc[r][1] * ad0.y + acc[r][2] * ad0.z + acc[r][3] * ad0.w
             + acc[r][4] * ad1.x + acc[r][5] * ad1.y + acc[r][6] * ad1.z + acc[r][7] * ad1.w;
    for (int off = 1; off < 16; off <<= 1) {
      ps += __shfl_xor(ps, off);
      pd += __shfl_xor(pd, off);
    }
    if (gn < N) {
      float4 o0 = make_float4(acc[r][0], acc[r][1], acc[r][2], acc[r][3]);
      float4 o1 = make_float4(acc[r][4], acc[r][5], acc[r][6], acc[r][7]);
      *(float4*)(Hout + gn * 128 + tx * 8) = o0;
      *(float4*)(Hout + gn * 128 + tx * 8 + 4) = o1;
      uint4 pb;
      pb.x = pk2bf(acc[r][0], acc[r][1]);
      pb.y = pk2bf(acc[r][2], acc[r][3]);
      pb.z = pk2bf(acc[r][4], acc[r][5]);
      pb.w = pk2bf(acc[r][6], acc[r][7]);
      Hbf[(size_t)gn * 16 + tx] = pb;
      if (tx == 0) { al_s[gn] = ps; al_d[gn] = pd; }
    }
  }
}

// per-dst softmax + aggregation. one wave per dst.
// Fast path (deg <= 64): lane owns one edge; softmax in registers;
//   pass C gathers from the bf16 table: one uint4 (8 bf16) per lane per
//   edge, converted in VALU, accumulated in f32. All shfls uniform-exec.
// Fallback (deg > 64): original 3-pass f32 path through exw.
__global__ __launch_bounds__(256) void k_agg(const int* __restrict__ csr_src,
                                             const int* __restrict__ rowp,
                                             const float* __restrict__ al_s,
                                             const float* __restrict__ al_d,
                                             const float* __restrict__ Hh,
                                             const uint4* __restrict__ Hbf,
                                             const float* __restrict__ bias,
                                             float* __restrict__ exw,
                                             float* __restrict__ Yout, int N, int relu) {
  int wid = threadIdx.x >> 6, lane = threadIdx.x & 63;
  int dst = blockIdx.x * 4 + wid;
  if (dst >= N) return;
  int beg = rowp[dst], end = rowp[dst + 1];
  int deg = end - beg;
  float ald = al_d[dst];

  int q = lane >> 4;       // quarter = edge offset within 4-edge group
  int l = lane & 15;       // feature lane: owns feats [l*8, l*8+8)
  float acc[8];
#pragma unroll
  for (int c = 0; c < 8; ++c) acc[c] = 0.f;

  if (deg <= 64) {
    // ---- register-resident softmax ----
    int srcv = 0;
    float e = -INFINITY;
    if (lane < deg) {
      srcv = csr_src[beg + lane];
      e = al_s[srcv] + ald;
      e = (e > 0.f) ? e : 0.2f * e;
    }
    float m = e;
    for (int off = 32; off; off >>= 1) m = fmaxf(m, __shfl_xor(m, off));
    float av = (lane < deg) ? __expf(e - m) : 0.f;
    float den = av;
    for (int off = 32; off; off >>= 1) den += __shfl_xor(den, off);
    av *= 1.0f / (den + 1e-16f);   // alpha, pre-normalized, in lane=edge

    int t = 0;
    for (; t + 8 <= deg; t += 8) {     // deg uniform: wave-uniform loop
      int sA = __shfl(srcv, t + q);
      int sB = __shfl(srcv, t + 4 + q);
      float wA = __shfl(av, t + q);
      float wB = __shfl(av, t + 4 + q);
      uint4 va = Hbf[(size_t)sA * 16 + l];
      uint4 vb = Hbf[(size_t)sB * 16 + l];
      acc[0] += wA * bflo(va.x) + wB * bflo(vb.x);
      acc[1] += wA * bfhi(va.x) + wB * bfhi(vb.x);
      acc[2] += wA * bflo(va.y) + wB * bflo(vb.y);
      acc[3] += wA * bfhi(va.y) + wB * bfhi(vb.y);
      acc[4] += wA * bflo(va.z) + wB * bflo(vb.z);
      acc[5] += wA * bfhi(va.z) + wB * bfhi(vb.z);
      acc[6] += wA * bflo(va.w) + wB * bflo(vb.w);
      acc[7] += wA * bfhi(va.w) + wB * bfhi(vb.w);
    }
    if (t + 4 <= deg) {                // uniform guard
      int sA = __shfl(srcv, t + q);
      float wA = __shfl(av, t + q);
      uint4 va = Hbf[(size_t)sA * 16 + l];
      acc[0] += wA * bflo(va.x); acc[1] += wA * bfhi(va.x);
      acc[2] += wA * bflo(va.y); acc[3] += wA * bfhi(va.y);
      acc[4] += wA * bflo(va.z); acc[5] += wA * bfhi(va.z);
      acc[6] += wA * bflo(va.w); acc[7] += wA * bfhi(va.w);
      t += 4;
    }
    {
      // tail: shfls hoisted OUT of the divergent guard (uniform exec)
      int sA = __shfl(srcv, t + q);
      float wA = __shfl(av, t + q);
      if (t + q < deg) {               // divergent: memory ops only
        uint4 va = Hbf[(size_t)sA * 16 + l];
        acc[0] += wA * bflo(va.x); acc[1] += wA * bfhi(va.x);
        acc[2] += wA * bflo(va.y); acc[3] += wA * bfhi(va.y);
        acc[4] += wA * bflo(va.z); acc[5] += wA * bfhi(va.z);
        acc[6] += wA * bflo(va.w); acc[7] += wA * bfhi(va.w);
      }
    }
  } else {
    // ---- generic fallback: 3-pass with per-edge scratch (f32 table) ----
    const float* Hl = Hh + l * 8;
    float m = -INFINITY;
    for (int j = beg + lane; j < end; j += 64) {
      float e = al_s[csr_src[j]] + ald;
      e = (e > 0.f) ? e : 0.2f * e;
      exw[j] = e;
      m = fmaxf(m, e);
    }
    for (int off = 32; off; off >>= 1) m = fmaxf(m, __shfl_xor(m, off));

    float den = 0.f;
    for (int j = beg + lane; j < end; j += 64) {
      float ex = __expf(exw[j] - m);
      exw[j] = ex;
      den += ex;
    }
    for (int off = 32; off; off >>= 1) den += __shfl_xor(den, off);
    float inv = 1.0f / (den + 1e-16f);

    int j = beg;
    for (; j + 8 <= end; j += 8) {
      int sA = csr_src[j + q];
      int sB = csr_src[j + 4 + q];
      float wA = exw[j + q] * inv;
      float wB = exw[j + 4 + q] * inv;
      const float* rA = Hl + (size_t)sA * 128;
      const float* rB = Hl + (size_t)sB * 128;
      float4 a0 = *(const float4*)(rA);
      float4 a1 = *(const float4*)(rA + 4);
      float4 b0 = *(const float4*)(rB);
      float4 b1 = *(const float4*)(rB + 4);
      acc[0] += wA * a0.x + wB * b0.x;
      acc[1] += wA * a0.y + wB * b0.y;
      acc[2] += wA * a0.z + wB * b0.z;
      acc[3] += wA * a0.w + wB * b0.w;
      acc[4] += wA * a1.x + wB * b1.x;
      acc[5] += wA * a1.y + wB * b1.y;
      acc[6] += wA * a1.z + wB * b1.z;
      acc[7] += wA * a1.w + wB * b1.w;
    }
    if (j + 4 <= end) {
      int sA = csr_src[j + q];
      float wA = exw[j + q] * inv;
      const float* rA = Hl + (size_t)sA * 128;
      float4 a0 = *(const float4*)(rA);
      float4 a1 = *(const float4*)(rA + 4);
      acc[0] += wA * a0.x; acc[1] += wA * a0.y; acc[2] += wA * a0.z; acc[3] += wA * a0.w;
      acc[4] += wA * a1.x; acc[5] += wA * a1.y; acc[6] += wA * a1.z; acc[7] += wA * a1.w;
      j += 4;
    }
    if (j + q < end) {
      int sA = csr_src[j + q];
      float wA = exw[j + q] * inv;
      const float* rA = Hl + (size_t)sA * 128;
      float4 a0 = *(const float4*)(rA);
      float4 a1 = *(const float4*)(rA + 4);
      acc[0] += wA * a0.x; acc[1] += wA * a0.y; acc[2] += wA * a0.z; acc[3] += wA * a0.w;
      acc[4] += wA * a1.x; acc[5] += wA * a1.y; acc[6] += wA * a1.z; acc[7] += wA * a1.w;
    }
  }

#pragma unroll
  for (int c = 0; c < 8; ++c) {
    acc[c] += __shfl_xor(acc[c], 16);
    acc[c] += __shfl_xor(acc[c], 32);
  }
  if (q == 0) {
    float4 bv0 = *(const float4*)(bias + l * 8);
    float4 bv1 = *(const float4*)(bias + l * 8 + 4);
    float4 o0 = make_float4(acc[0] + bv0.x, acc[1] + bv0.y, acc[2] + bv0.z, acc[3] + bv0.w);
    float4 o1 = make_float4(acc[4] + bv1.x, acc[5] + bv1.y, acc[6] + bv1.z, acc[7] + bv1.w);
    if (relu) {
      o0.x = fmaxf(o0.x, 0.f); o0.y = fmaxf(o0.y, 0.f); o0.z = fmaxf(o0.z, 0.f); o0.w = fmaxf(o0.w, 0.f);
      o1.x = fmaxf(o1.x, 0.f); o1.y = fmaxf(o1.y, 0.f); o1.z = fmaxf(o1.z, 0.f); o1.w = fmaxf(o1.w, 0.f);
    }
    *(float4*)(Yout + (size_t)dst * 128 + l * 8) = o0;
    *(float4*)(Yout + (size_t)dst * 128 + l * 8 + 4) = o1;
  }
}

// run-length pooling over sorted batch
__global__ __launch_bounds__(256) void k_pool(const float* __restrict__ Hh,
                                              const int* __restrict__ batch,
                                              float* __restrict__ gsum,
                                              float* __restrict__ gcnt,
                                              int N, int nwaves) {
  int gw = (blockIdx.x * 256 + threadIdx.x) >> 6;
  int lane = threadIdx.x & 63;
  int chunk = (N + nwaves - 1) / nwaves;
  int beg = gw * chunk;
  int end = beg + chunk; if (end > N) end = N;
  if (beg >= end) return;

  int curg = batch[beg];
  float2 acc = {0.f, 0.f};
  int cnt = 0;
  for (int n = beg; n < end; ++n) {
    int g = batch[n];
    if (g != curg) {
      atomicAdd(&gsum[curg * 128 + lane * 2], acc.x);
      atomicAdd(&gsum[curg * 128 + lane * 2 + 1], acc.y);
      if (lane == 0) atomicAdd(&gcnt[curg], (float)cnt);
      acc.x = 0.f; acc.y = 0.f; cnt = 0; curg = g;
    }
    float2 h = *(const float2*)(Hh + (size_t)n * 128 + lane * 2);
    acc.x += h.x; acc.y += h.y; ++cnt;
  }
  atomicAdd(&gsum[curg * 128 + lane * 2], acc.x);
  atomicAdd(&gsum[curg * 128 + lane * 2 + 1], acc.y);
  if (lane == 0) atomicAdd(&gcnt[curg], (float)cnt);
}

__global__ __launch_bounds__(128) void k_final(const float* __restrict__ gsum,
                                               const float* __restrict__ gcnt,
                                               const float* __restrict__ Wlin,
                                               const float* __restrict__ blin,
                                               float* __restrict__ out) {
  int t = threadIdx.x;  // 128 threads: (g, c) pairs
  int g = t >> 1, c = t & 1;
  float inv = 1.0f / fmaxf(gcnt[g], 1.0f);
  float acc = blin[c];
  for (int k = 0; k < 128; ++k) acc += gsum[g * 128 + k] * inv * Wlin[k * 2 + c];
  out[g * 2 + c] = acc;
}

extern "C" void kernel_launch(void* const* d_in, const int* in_sizes, int n_in,
                              void* d_out, int out_size, void* d_ws, size_t ws_size,
                              hipStream_t stream) {
  const float* x    = (const float*)d_in[0];
  const int*   ei   = (const int*)d_in[1];
  const int*   batch= (const int*)d_in[2];
  const float* W1   = (const float*)d_in[3];
  const float* as1  = (const float*)d_in[4];
  const float* ad1  = (const float*)d_in[5];
  const float* b1   = (const float*)d_in[6];
  const float* W2   = (const float*)d_in[7];
  const float* as2  = (const float*)d_in[8];
  const float* ad2  = (const float*)d_in[9];
  const float* b2   = (const float*)d_in[10];
  const float* W3   = (const float*)d_in[11];
  const float* as3  = (const float*)d_in[12];
  const float* ad3  = (const float*)d_in[13];
  const float* b3   = (const float*)d_in[14];
  const float* Wlin = (const float*)d_in[15];
  const float* blin = (const float*)d_in[16];

  int N = in_sizes[0] / 4;
  int E = in_sizes[1] / 2;
  int ET = E + N;

  char* ws = (char*)d_ws;
  float* bufA = (float*)ws; ws += (size_t)N * 128 * 4;
  float* bufB = (float*)ws; ws += (size_t)N * 128 * 4;
  unsigned* hbf = (unsigned*)ws; ws += (size_t)N * 128 * 2;   // bf16 gather table
  float* al_s = (float*)ws; ws += (size_t)N * 4;
  float* al_d = (float*)ws; ws += (size_t)N * 4;
  float* gsum = (float*)ws; ws += (size_t)64 * 128 * 4;
  float* gcnt = (float*)ws; ws += (size_t)64 * 4;
  int* rowp   = (int*)ws;   ws += (size_t)(N + 1) * 4;
  int* cursor = (int*)ws;   ws += (size_t)N * 4;
  int* csr    = (int*)ws;   ws += (size_t)ET * 4;
  float* exw  = (float*)ws; ws += (size_t)ET * 4;
  int* bsum   = (int*)ws;   ws += (size_t)256 * 4;

  hipMemsetAsync(cursor, 0, (size_t)N * 4, stream);
  hipMemsetAsync(gsum, 0, (size_t)(64 * 128 + 64) * 4, stream);  // gsum + gcnt

  int eb = (ET + 255) / 256;
  int nsb = (N + 1023) / 1024;  // scan blocks (<=256)
  k_count  <<<eb, 256, 0, stream>>>(ei, cursor, E, N);
  k_scan1  <<<nsb, 256, 0, stream>>>(cursor, rowp, bsum, N);
  k_scan2  <<<1, 256, 0, stream>>>(bsum, nsb);
  k_scan3  <<<nsb, 256, 0, stream>>>(rowp, cursor, bsum, N, ET);
  k_scatter<<<eb, 256, 0, stream>>>(ei, cursor, csr, E, N);

  int nb4 = (N + 3) / 4;
  // layer 1
  k_gemm4al<<<nb4, 256, 0, stream>>>(x, W1, as1, ad1, bufA, hbf, al_s, al_d, N);
  k_agg    <<<nb4, 256, 0, stream>>>(csr, rowp, al_s, al_d, bufA, (const uint4*)hbf, b1, exw, bufB, N, 1);
  // layer 2
  k_gemm128al<<<(N + 63) / 64, 256, 0, stream>>>(bufB, W2, as2, ad2, bufA, (uint4*)hbf, al_s, al_d, N);
  k_agg      <<<nb4, 256, 0, stream>>>(csr, rowp, al_s, al_d, bufA, (const uint4*)hbf, b2, exw, bufB, N, 1);
  // layer 3
  k_gemm128al<<<(N + 63) / 64, 256, 0, stream>>>(bufB, W3, as3, ad3, bufA, (uint4*)hbf, al_s, al_d, N);
  k_agg      <<<nb4, 256, 0, stream>>>(csr, rowp, al_s, al_d, bufA, (const uint4*)hbf, b3, exw, bufB, N, 0);

  // global mean pool + linear head (256 blocks x 4 waves = 1024 waves)
  k_pool <<<256, 256, 0, stream>>>(bufB, batch, gsum, gcnt, N, 1024);
  k_final<<<1, 128, 0, stream>>>(gsum, gcnt, Wlin, blin, (float*)d_out);
}

// Round 4
// 368.911 us; speedup vs baseline: 1.3204x; 1.1437x over previous
//
#include <hip/hip_runtime.h>
#include <math.h>

// ---------------------------------------------------------------------------
// GAT 3-layer net. CSR by dst built once per call; per-layer:
//   gemm+al fused (h = X@W, al_s/al_d epilogue), agg (per-dst softmax+gather).
// R1: k_pool run-length accumulation (batch sorted).
// R2-R3: scratch softmax passes; hierarchical scan.
// R4: k_agg pass C quarter-wave-per-edge; al fused into gemm epilogues.
// R5/R6: k_agg register-resident softmax (lane-per-edge, uniform-exec shfls).
// R7: bf16 gather table (16B/lane/edge) — halves gather traffic + L2 set.
// R8: CSR build rewritten as bucketed counting sort. Old k_count/k_scan1-3/
//     k_scatter did 850k random 4B stores -> 54.5MB of partial-line
//     writebacks (~60us) plus random atomics (k_count). New: LDS bucket
//     histogram -> 1-WG scan -> run-reserved partition (dense packed runs)
//     -> per-bucket LDS counting-sort producing coalesced rowp writes and
//     csr writes confined to the bucket's contiguous window. All global
//     writes are dense; per-WG windows keep lines fully dirtied.
//     Requires N <= 65536 (pack src<<9|dstlocal); N=50000 here.
// ---------------------------------------------------------------------------

#define BW 512          // nodes per bucket (power of 2)
#define PART_CHUNK 4096 // edges per WG in kb_part

__device__ __forceinline__ float bflo(unsigned u) { return __uint_as_float(u << 16); }
__device__ __forceinline__ float bfhi(unsigned u) { return __uint_as_float(u & 0xffff0000u); }
// pack two f32 -> two bf16 (round-nearest-even), a in low half, b in high
__device__ __forceinline__ unsigned pk2bf(float a, float b) {
  unsigned ua = __float_as_uint(a); ua += 0x7fffu + ((ua >> 16) & 1u);
  unsigned ub = __float_as_uint(b); ub += 0x7fffu + ((ub >> 16) & 1u);
  return (ua >> 16) | (ub & 0xffff0000u);
}

// ---- CSR build, stage 1: per-bucket edge counts (LDS histogram) ----
__global__ __launch_bounds__(256) void kb_hist(const int* __restrict__ ei,
                                               int* __restrict__ bcnt,
                                               int E, int ET, int NB) {
  __shared__ int h[128];
  int tid = threadIdx.x;
  if (tid < 128) h[tid] = 0;
  __syncthreads();
  int stride = gridDim.x * 256;
  for (int i = blockIdx.x * 256 + tid; i < ET; i += stride) {
    int dst = (i < E) ? ei[E + i] : (i - E);
    atomicAdd(&h[dst >> 9], 1);
  }
  __syncthreads();
  if (tid < NB && h[tid] > 0) atomicAdd(&bcnt[tid], h[tid]);
}

// ---- stage 2: 1 WG exclusive-scans NB (<=128) bucket counts ----
__global__ __launch_bounds__(128) void kb_scan(const int* __restrict__ bcnt,
                                               int* __restrict__ bbase,
                                               int* __restrict__ bcur,
                                               int* __restrict__ rowp,
                                               int N, int ET, int NB) {
  __shared__ int sm[128];
  int t = threadIdx.x;
  int v = (t < NB) ? bcnt[t] : 0;
  sm[t] = v;
  __syncthreads();
  for (int off = 1; off < 128; off <<= 1) {
    int u = (t >= off) ? sm[t - off] : 0;
    __syncthreads();
    sm[t] += u;
    __syncthreads();
  }
  int pre = sm[t] - v;                  // exclusive
  if (t <= NB) bbase[t] = pre;          // bbase[NB] == ET
  if (t < NB) bcur[t] = pre;
  if (t == 0) rowp[N] = ET;
}

// ---- stage 3: partition edges into bucket runs (packed src<<9|dstlocal) ----
__global__ __launch_bounds__(256) void kb_part(const int* __restrict__ ei,
                                               int* __restrict__ bcur,
                                               int* __restrict__ bucketed,
                                               int E, int ET, int NB) {
  __shared__ int hist[128];
  __shared__ int runb[128];
  int tid = threadIdx.x;
  int base = blockIdx.x * PART_CHUNK;
  if (tid < 128) hist[tid] = 0;

  int sv[16], dv[16];
#pragma unroll
  for (int k = 0; k < 16; ++k) {
    int j = base + k * 256 + tid;
    int s = -1, d = 0;
    if (j < ET) {
      if (j < E) { s = ei[j]; d = ei[E + j]; }
      else       { s = j - E; d = j - E; }
    }
    sv[k] = s; dv[k] = d;
  }
  __syncthreads();
#pragma unroll
  for (int k = 0; k < 16; ++k)
    if (sv[k] >= 0) atomicAdd(&hist[dv[k] >> 9], 1);
  __syncthreads();
  if (tid < NB && hist[tid] > 0) runb[tid] = atomicAdd(&bcur[tid], hist[tid]);
  __syncthreads();
  if (tid < 128) hist[tid] = 0;   // reuse as within-run cursor
  __syncthreads();
#pragma unroll
  for (int k = 0; k < 16; ++k) {
    if (sv[k] >= 0) {
      int b = dv[k] >> 9;
      int off = atomicAdd(&hist[b], 1);
      bucketed[runb[b] + off] = (sv[k] << 9) | (dv[k] & (BW - 1));
    }
  }
}

// ---- stage 4: per-bucket counting sort -> rowp segment + csr window ----
__global__ __launch_bounds__(256) void kb_csr(const int* __restrict__ bucketed,
                                              const int* __restrict__ bbase,
                                              int* __restrict__ rowp,
                                              int* __restrict__ csr,
                                              int N) {
  __shared__ int h[512];
  __shared__ int sm[256];
  __shared__ int cur[512];
  int tid = threadIdx.x;
  int b = blockIdx.x;
  int cb = bbase[b], ce = bbase[b + 1];

  h[tid] = 0; h[tid + 256] = 0;
  __syncthreads();
  for (int j = cb + tid; j < ce; j += 256)
    atomicAdd(&h[bucketed[j] & (BW - 1)], 1);
  __syncthreads();
  int a0 = h[2 * tid], a1 = h[2 * tid + 1];
  int s = a0 + a1;
  sm[tid] = s;
  __syncthreads();
  for (int off = 1; off < 256; off <<= 1) {
    int u = (tid >= off) ? sm[tid - off] : 0;
    __syncthreads();
    sm[tid] += u;
    __syncthreads();
  }
  int pre = sm[tid] - s;                 // exclusive over pairs
  cur[2 * tid] = pre;
  cur[2 * tid + 1] = pre + a0;
  __syncthreads();
  int node0 = b * BW;
  for (int local = tid; local < BW; local += 256) {
    int node = node0 + local;
    if (node < N) rowp[node] = cb + cur[local];   // coalesced segment write
  }
  __syncthreads();
  for (int j = cb + tid; j < ce; j += 256) {
    int p = bucketed[j];
    int loc = p & (BW - 1);
    int pos = cb + atomicAdd(&cur[loc], 1);
    csr[pos] = (unsigned)p >> 9;          // confined to [cb,ce) window
  }
}

// layer-1 GEMM fused with al: one wave per node, lane owns 2 features.
__global__ __launch_bounds__(256) void k_gemm4al(const float* __restrict__ X,
                                                 const float* __restrict__ W,
                                                 const float* __restrict__ asv,
                                                 const float* __restrict__ adv,
                                                 float* __restrict__ Hout,
                                                 unsigned* __restrict__ Hbf,
                                                 float* __restrict__ al_s,
                                                 float* __restrict__ al_d, int N) {
  int wid = threadIdx.x >> 6, lane = threadIdx.x & 63;
  int node = blockIdx.x * 4 + wid;
  if (node >= N) return;
  float4 xv = *(const float4*)(X + node * 4);
  int f = lane * 2;
  float2 w0 = *(const float2*)(W + f);
  float2 w1 = *(const float2*)(W + 128 + f);
  float2 w2 = *(const float2*)(W + 256 + f);
  float2 w3 = *(const float2*)(W + 384 + f);
  float h0 = xv.x * w0.x + xv.y * w1.x + xv.z * w2.x + xv.w * w3.x;
  float h1 = xv.x * w0.y + xv.y * w1.y + xv.z * w2.y + xv.w * w3.y;
  float2 hv = {h0, h1};
  *(float2*)(Hout + node * 128 + f) = hv;
  Hbf[node * 64 + lane] = pk2bf(h0, h1);
  float2 s2 = *(const float2*)(asv + f);
  float2 d2 = *(const float2*)(adv + f);
  float ps = h0 * s2.x + h1 * s2.y;
  float pd = h0 * d2.x + h1 * d2.y;
  for (int off = 32; off; off >>= 1) {
    ps += __shfl_xor(ps, off);
    pd += __shfl_xor(pd, off);
  }
  if (lane == 0) { al_s[node] = ps; al_d[node] = pd; }
}

// GEMM: X [N,128] @ W [128,128] -> Hout [N,128] (+bf16 copy), fused al epilogue.
__global__ __launch_bounds__(256) void k_gemm128al(const float* __restrict__ X,
                                                   const float* __restrict__ W,
                                                   const float* __restrict__ asv,
                                                   const float* __restrict__ adv,
                                                   float* __restrict__ Hout,
                                                   uint4* __restrict__ Hbf,
                                                   float* __restrict__ al_s,
                                                   float* __restrict__ al_d, int N) {
  __shared__ float Ws[64 * 128];    // 32 KB
  __shared__ float Xs[64 * 68];     // 17 KB
  int tid = threadIdx.x;
  int base = blockIdx.x * 64;
  int ty = tid >> 4, tx = tid & 15;

  float acc[4][8];
#pragma unroll
  for (int r = 0; r < 4; ++r)
#pragma unroll
    for (int c = 0; c < 8; ++c) acc[r][c] = 0.f;

  for (int kk = 0; kk < 128; kk += 64) {
    __syncthreads();
    for (int i = tid * 4; i < 64 * 128; i += 1024) {
      *(float4*)(Ws + i) = *(const float4*)(W + kk * 128 + i);
    }
    for (int i = tid; i < 64 * 16; i += 256) {
      int node = i >> 4, k4 = (i & 15) << 2;
      int gn = base + node;
      float4 v;
      if (gn < N) v = *(const float4*)(X + gn * 128 + kk + k4);
      else        v = make_float4(0.f, 0.f, 0.f, 0.f);
      *(float4*)(Xs + node * 68 + k4) = v;
    }
    __syncthreads();

    for (int k = 0; k < 64; ++k) {
      float a0 = Xs[(ty * 4 + 0) * 68 + k];
      float a1 = Xs[(ty * 4 + 1) * 68 + k];
      float a2 = Xs[(ty * 4 + 2) * 68 + k];
      float a3 = Xs[(ty * 4 + 3) * 68 + k];
      float4 b0 = *(const float4*)(Ws + k * 128 + tx * 8);
      float4 b1 = *(const float4*)(Ws + k * 128 + tx * 8 + 4);
      acc[0][0] += a0 * b0.x; acc[0][1] += a0 * b0.y; acc[0][2] += a0 * b0.z; acc[0][3] += a0 * b0.w;
      acc[0][4] += a0 * b1.x; acc[0][5] += a0 * b1.y; acc[0][6] += a0 * b1.z; acc[0][7] += a0 * b1.w;
      acc[1][0] += a1 * b0.x; acc[1][1] += a1 * b0.y; acc[1][2] += a1 * b0.z; acc[1][3] += a1 * b0.w;
      acc[1][4] += a1 * b1.x; acc[1][5] += a1 * b1.y; acc[1][6] += a1 * b1.z; acc[1][7] += a1 * b1.w;
      acc[2][0] += a2 * b0.x; acc[2][1] += a2 * b0.y; acc[2][2] += a2 * b0.z; acc[2][3] += a2 * b0.w;
      acc[2][4] += a2 * b1.x; acc[2][5] += a2 * b1.y; acc[2][6] += a2 * b1.z; acc[2][7] += a2 * b1.w;
      acc[3][0] += a3 * b0.x; acc[3][1] += a3 * b0.y; acc[3][2] += a3 * b0.z; acc[3][3] += a3 * b0.w;
      acc[3][4] += a3 * b1.x; acc[3][5] += a3 * b1.y; acc[3][6] += a3 * b1.z; acc[3][7] += a3 * b1.w;
    }
  }

  // epilogue: store h (f32 + bf16) and fused al reduction
  float4 as0 = *(const float4*)(asv + tx * 8);
  float4 as1 = *(const float4*)(asv + tx * 8 + 4);
  float4 ad0 = *(const float4*)(adv + tx * 8);
  float4 ad1 = *(const float4*)(adv + tx * 8 + 4);
#pragma unroll
  for (int r = 0; r < 4; ++r) {
    int gn = base + ty * 4 + r;
    float ps = acc[r][0] * as0.x + acc[r][1] * as0.y + acc[r][2] * as0.z + acc[r][3] * as0.w
             + acc[r][4] * as1.x + acc[r][5] * as1.y + acc[r][6] * as1.z + acc[r][7] * as1.w;
    float pd = acc[r][0] * ad0.x + acc[r][1] * ad0.y + acc[r][2] * ad0.z + acc[r][3] * ad0.w
             + acc[r][4] * ad1.x + acc[r][5] * ad1.y + acc[r][6] * ad1.z + acc[r][7] * ad1.w;
    for (int off = 1; off < 16; off <<= 1) {
      ps += __shfl_xor(ps, off);
      pd += __shfl_xor(pd, off);
    }
    if (gn < N) {
      float4 o0 = make_float4(acc[r][0], acc[r][1], acc[r][2], acc[r][3]);
      float4 o1 = make_float4(acc[r][4], acc[r][5], acc[r][6], acc[r][7]);
      *(float4*)(Hout + gn * 128 + tx * 8) = o0;
      *(float4*)(Hout + gn * 128 + tx * 8 + 4) = o1;
      uint4 pb;
      pb.x = pk2bf(acc[r][0], acc[r][1]);
      pb.y = pk2bf(acc[r][2], acc[r][3]);
      pb.z = pk2bf(acc[r][4], acc[r][5]);
      pb.w = pk2bf(acc[r][6], acc[r][7]);
      Hbf[(size_t)gn * 16 + tx] = pb;
      if (tx == 0) { al_s[gn] = ps; al_d[gn] = pd; }
    }
  }
}

// per-dst softmax + aggregation. one wave per dst.
// Fast path (deg <= 64): lane owns one edge; softmax in registers;
//   pass C gathers from the bf16 table: one uint4 (8 bf16) per lane per
//   edge, converted in VALU, accumulated in f32. All shfls uniform-exec.
// Fallback (deg > 64): original 3-pass f32 path through exw.
__global__ __launch_bounds__(256) void k_agg(const int* __restrict__ csr_src,
                                             const int* __restrict__ rowp,
                                             const float* __restrict__ al_s,
                                             const float* __restrict__ al_d,
                                             const float* __restrict__ Hh,
                                             const uint4* __restrict__ Hbf,
                                             const float* __restrict__ bias,
                                             float* __restrict__ exw,
                                             float* __restrict__ Yout, int N, int relu) {
  int wid = threadIdx.x >> 6, lane = threadIdx.x & 63;
  int dst = blockIdx.x * 4 + wid;
  if (dst >= N) return;
  int beg = rowp[dst], end = rowp[dst + 1];
  int deg = end - beg;
  float ald = al_d[dst];

  int q = lane >> 4;       // quarter = edge offset within 4-edge group
  int l = lane & 15;       // feature lane: owns feats [l*8, l*8+8)
  float acc[8];
#pragma unroll
  for (int c = 0; c < 8; ++c) acc[c] = 0.f;

  if (deg <= 64) {
    // ---- register-resident softmax ----
    int srcv = 0;
    float e = -INFINITY;
    if (lane < deg) {
      srcv = csr_src[beg + lane];
      e = al_s[srcv] + ald;
      e = (e > 0.f) ? e : 0.2f * e;
    }
    float m = e;
    for (int off = 32; off; off >>= 1) m = fmaxf(m, __shfl_xor(m, off));
    float av = (lane < deg) ? __expf(e - m) : 0.f;
    float den = av;
    for (int off = 32; off; off >>= 1) den += __shfl_xor(den, off);
    av *= 1.0f / (den + 1e-16f);   // alpha, pre-normalized, in lane=edge

    int t = 0;
    for (; t + 8 <= deg; t += 8) {     // deg uniform: wave-uniform loop
      int sA = __shfl(srcv, t + q);
      int sB = __shfl(srcv, t + 4 + q);
      float wA = __shfl(av, t + q);
      float wB = __shfl(av, t + 4 + q);
      uint4 va = Hbf[(size_t)sA * 16 + l];
      uint4 vb = Hbf[(size_t)sB * 16 + l];
      acc[0] += wA * bflo(va.x) + wB * bflo(vb.x);
      acc[1] += wA * bfhi(va.x) + wB * bfhi(vb.x);
      acc[2] += wA * bflo(va.y) + wB * bflo(vb.y);
      acc[3] += wA * bfhi(va.y) + wB * bfhi(vb.y);
      acc[4] += wA * bflo(va.z) + wB * bflo(vb.z);
      acc[5] += wA * bfhi(va.z) + wB * bfhi(vb.z);
      acc[6] += wA * bflo(va.w) + wB * bflo(vb.w);
      acc[7] += wA * bfhi(va.w) + wB * bfhi(vb.w);
    }
    if (t + 4 <= deg) {                // uniform guard
      int sA = __shfl(srcv, t + q);
      float wA = __shfl(av, t + q);
      uint4 va = Hbf[(size_t)sA * 16 + l];
      acc[0] += wA * bflo(va.x); acc[1] += wA * bfhi(va.x);
      acc[2] += wA * bflo(va.y); acc[3] += wA * bfhi(va.y);
      acc[4] += wA * bflo(va.z); acc[5] += wA * bfhi(va.z);
      acc[6] += wA * bflo(va.w); acc[7] += wA * bfhi(va.w);
      t += 4;
    }
    {
      // tail: shfls hoisted OUT of the divergent guard (uniform exec)
      int sA = __shfl(srcv, t + q);
      float wA = __shfl(av, t + q);
      if (t + q < deg) {               // divergent: memory ops only
        uint4 va = Hbf[(size_t)sA * 16 + l];
        acc[0] += wA * bflo(va.x); acc[1] += wA * bfhi(va.x);
        acc[2] += wA * bflo(va.y); acc[3] += wA * bfhi(va.y);
        acc[4] += wA * bflo(va.z); acc[5] += wA * bfhi(va.z);
        acc[6] += wA * bflo(va.w); acc[7] += wA * bfhi(va.w);
      }
    }
  } else {
    // ---- generic fallback: 3-pass with per-edge scratch (f32 table) ----
    const float* Hl = Hh + l * 8;
    float m = -INFINITY;
    for (int j = beg + lane; j < end; j += 64) {
      float e = al_s[csr_src[j]] + ald;
      e = (e > 0.f) ? e : 0.2f * e;
      exw[j] = e;
      m = fmaxf(m, e);
    }
    for (int off = 32; off; off >>= 1) m = fmaxf(m, __shfl_xor(m, off));

    float den = 0.f;
    for (int j = beg + lane; j < end; j += 64) {
      float ex = __expf(exw[j] - m);
      exw[j] = ex;
      den += ex;
    }
    for (int off = 32; off; off >>= 1) den += __shfl_xor(den, off);
    float inv = 1.0f / (den + 1e-16f);

    int j = beg;
    for (; j + 8 <= end; j += 8) {
      int sA = csr_src[j + q];
      int sB = csr_src[j + 4 + q];
      float wA = exw[j + q] * inv;
      float wB = exw[j + 4 + q] * inv;
      const float* rA = Hl + (size_t)sA * 128;
      const float* rB = Hl + (size_t)sB * 128;
      float4 a0 = *(const float4*)(rA);
      float4 a1 = *(const float4*)(rA + 4);
      float4 b0 = *(const float4*)(rB);
      float4 b1 = *(const float4*)(rB + 4);
      acc[0] += wA * a0.x + wB * b0.x;
      acc[1] += wA * a0.y + wB * b0.y;
      acc[2] += wA * a0.z + wB * b0.z;
      acc[3] += wA * a0.w + wB * b0.w;
      acc[4] += wA * a1.x + wB * b1.x;
      acc[5] += wA * a1.y + wB * b1.y;
      acc[6] += wA * a1.z + wB * b1.z;
      acc[7] += wA * a1.w + wB * b1.w;
    }
    if (j + 4 <= end) {
      int sA = csr_src[j + q];
      float wA = exw[j + q] * inv;
      const float* rA = Hl + (size_t)sA * 128;
      float4 a0 = *(const float4*)(rA);
      float4 a1 = *(const float4*)(rA + 4);
      acc[0] += wA * a0.x; acc[1] += wA * a0.y; acc[2] += wA * a0.z; acc[3] += wA * a0.w;
      acc[4] += wA * a1.x; acc[5] += wA * a1.y; acc[6] += wA * a1.z; acc[7] += wA * a1.w;
      j += 4;
    }
    if (j + q < end) {
      int sA = csr_src[j + q];
      float wA = exw[j + q] * inv;
      const float* rA = Hl + (size_t)sA * 128;
      float4 a0 = *(const float4*)(rA);
      float4 a1 = *(const float4*)(rA + 4);
      acc[0] += wA * a0.x; acc[1] += wA * a0.y; acc[2] += wA * a0.z; acc[3] += wA * a0.w;
      acc[4] += wA * a1.x; acc[5] += wA * a1.y; acc[6] += wA * a1.z; acc[7] += wA * a1.w;
    }
  }

#pragma unroll
  for (int c = 0; c < 8; ++c) {
    acc[c] += __shfl_xor(acc[c], 16);
    acc[c] += __shfl_xor(acc[c], 32);
  }
  if (q == 0) {
    float4 bv0 = *(const float4*)(bias + l * 8);
    float4 bv1 = *(const float4*)(bias + l * 8 + 4);
    float4 o0 = make_float4(acc[0] + bv0.x, acc[1] + bv0.y, acc[2] + bv0.z, acc[3] + bv0.w);
    float4 o1 = make_float4(acc[4] + bv1.x, acc[5] + bv1.y, acc[6] + bv1.z, acc[7] + bv1.w);
    if (relu) {
      o0.x = fmaxf(o0.x, 0.f); o0.y = fmaxf(o0.y, 0.f); o0.z = fmaxf(o0.z, 0.f); o0.w = fmaxf(o0.w, 0.f);
      o1.x = fmaxf(o1.x, 0.f); o1.y = fmaxf(o1.y, 0.f); o1.z = fmaxf(o1.z, 0.f); o1.w = fmaxf(o1.w, 0.f);
    }
    *(float4*)(Yout + (size_t)dst * 128 + l * 8) = o0;
    *(float4*)(Yout + (size_t)dst * 128 + l * 8 + 4) = o1;
  }
}

// run-length pooling over sorted batch
__global__ __launch_bounds__(256) void k_pool(const float* __restrict__ Hh,
                                              const int* __restrict__ batch,
                                              float* __restrict__ gsum,
                                              float* __restrict__ gcnt,
                                              int N, int nwaves) {
  int gw = (blockIdx.x * 256 + threadIdx.x) >> 6;
  int lane = threadIdx.x & 63;
  int chunk = (N + nwaves - 1) / nwaves;
  int beg = gw * chunk;
  int end = beg + chunk; if (end > N) end = N;
  if (beg >= end) return;

  int curg = batch[beg];
  float2 acc = {0.f, 0.f};
  int cnt = 0;
  for (int n = beg; n < end; ++n) {
    int g = batch[n];
    if (g != curg) {
      atomicAdd(&gsum[curg * 128 + lane * 2], acc.x);
      atomicAdd(&gsum[curg * 128 + lane * 2 + 1], acc.y);
      if (lane == 0) atomicAdd(&gcnt[curg], (float)cnt);
      acc.x = 0.f; acc.y = 0.f; cnt = 0; curg = g;
    }
    float2 h = *(const float2*)(Hh + (size_t)n * 128 + lane * 2);
    acc.x += h.x; acc.y += h.y; ++cnt;
  }
  atomicAdd(&gsum[curg * 128 + lane * 2], acc.x);
  atomicAdd(&gsum[curg * 128 + lane * 2 + 1], acc.y);
  if (lane == 0) atomicAdd(&gcnt[curg], (float)cnt);
}

__global__ __launch_bounds__(128) void k_final(const float* __restrict__ gsum,
                                               const float* __restrict__ gcnt,
                                               const float* __restrict__ Wlin,
                                               const float* __restrict__ blin,
                                               float* __restrict__ out) {
  int t = threadIdx.x;  // 128 threads: (g, c) pairs
  int g = t >> 1, c = t & 1;
  float inv = 1.0f / fmaxf(gcnt[g], 1.0f);
  float acc = blin[c];
  for (int k = 0; k < 128; ++k) acc += gsum[g * 128 + k] * inv * Wlin[k * 2 + c];
  out[g * 2 + c] = acc;
}

extern "C" void kernel_launch(void* const* d_in, const int* in_sizes, int n_in,
                              void* d_out, int out_size, void* d_ws, size_t ws_size,
                              hipStream_t stream) {
  const float* x    = (const float*)d_in[0];
  const int*   ei   = (const int*)d_in[1];
  const int*   batch= (const int*)d_in[2];
  const float* W1   = (const float*)d_in[3];
  const float* as1  = (const float*)d_in[4];
  const float* ad1  = (const float*)d_in[5];
  const float* b1   = (const float*)d_in[6];
  const float* W2   = (const float*)d_in[7];
  const float* as2  = (const float*)d_in[8];
  const float* ad2  = (const float*)d_in[9];
  const float* b2   = (const float*)d_in[10];
  const float* W3   = (const float*)d_in[11];
  const float* as3  = (const float*)d_in[12];
  const float* ad3  = (const float*)d_in[13];
  const float* b3   = (const float*)d_in[14];
  const float* Wlin = (const float*)d_in[15];
  const float* blin = (const float*)d_in[16];

  int N = in_sizes[0] / 4;
  int E = in_sizes[1] / 2;
  int ET = E + N;
  int NB = (N + BW - 1) / BW;   // buckets (<=128 for N<=65536)

  char* ws = (char*)d_ws;
  float* bufA = (float*)ws; ws += (size_t)N * 128 * 4;
  float* bufB = (float*)ws; ws += (size_t)N * 128 * 4;
  unsigned* hbf = (unsigned*)ws; ws += (size_t)N * 128 * 2;   // bf16 gather table
  float* al_s = (float*)ws; ws += (size_t)N * 4;
  float* al_d = (float*)ws; ws += (size_t)N * 4;
  float* gsum = (float*)ws; ws += (size_t)64 * 128 * 4;
  float* gcnt = (float*)ws; ws += (size_t)64 * 4;
  int* rowp   = (int*)ws;   ws += (size_t)(N + 1) * 4;
  int* csr    = (int*)ws;   ws += (size_t)ET * 4;
  float* exw  = (float*)ws; ws += (size_t)ET * 4;
  int* bucketed = (int*)ws; ws += (size_t)ET * 4;
  int* bcnt   = (int*)ws;   ws += (size_t)128 * 4;
  int* bbase  = (int*)ws;   ws += (size_t)132 * 4;
  int* bcur   = (int*)ws;   ws += (size_t)128 * 4;

  hipMemsetAsync(bcnt, 0, (size_t)128 * 4, stream);
  hipMemsetAsync(gsum, 0, (size_t)(64 * 128 + 64) * 4, stream);  // gsum + gcnt

  // CSR build (bucketed counting sort)
  kb_hist<<<256, 256, 0, stream>>>(ei, bcnt, E, ET, NB);
  kb_scan<<<1, 128, 0, stream>>>(bcnt, bbase, bcur, rowp, N, ET, NB);
  kb_part<<<(ET + PART_CHUNK - 1) / PART_CHUNK, 256, 0, stream>>>(ei, bcur, bucketed, E, ET, NB);
  kb_csr <<<NB, 256, 0, stream>>>(bucketed, bbase, rowp, csr, N);

  int nb4 = (N + 3) / 4;
  // layer 1
  k_gemm4al<<<nb4, 256, 0, stream>>>(x, W1, as1, ad1, bufA, hbf, al_s, al_d, N);
  k_agg    <<<nb4, 256, 0, stream>>>(csr, rowp, al_s, al_d, bufA, (const uint4*)hbf, b1, exw, bufB, N, 1);
  // layer 2
  k_gemm128al<<<(N + 63) / 64, 256, 0, stream>>>(bufB, W2, as2, ad2, bufA, (uint4*)hbf, al_s, al_d, N);
  k_agg      <<<nb4, 256, 0, stream>>>(csr, rowp, al_s, al_d, bufA, (const uint4*)hbf, b2, exw, bufB, N, 1);
  // layer 3
  k_gemm128al<<<(N + 63) / 64, 256, 0, stream>>>(bufB, W3, as3, ad3, bufA, (uint4*)hbf, al_s, al_d, N);
  k_agg      <<<nb4, 256, 0, stream>>>(csr, rowp, al_s, al_d, bufA, (const uint4*)hbf, b3, exw, bufB, N, 0);

  // global mean pool + linear head (256 blocks x 4 waves = 1024 waves)
  k_pool <<<256, 256, 0, stream>>>(bufB, batch, gsum, gcnt, N, 1024);
  k_final<<<1, 128, 0, stream>>>(gsum, gcnt, Wlin, blin, (float*)d_out);
}

// Round 5
// 346.919 us; speedup vs baseline: 1.4041x; 1.0634x over previous
//
#include <hip/hip_runtime.h>
#include <math.h>

// ---------------------------------------------------------------------------
// GAT 3-layer net. CSR by dst built once per call (bucketed counting sort);
// per-layer: gemm+al fused, agg (per-dst softmax+gather).
// R1-R4: pool run-length; scans; quarter-wave gather; al fused epilogues.
// R5/R6: k_agg register softmax (lane-per-edge, uniform-exec shfls).
// R7: bf16 gather table (16B/lane/edge).
// R8: bucketed counting-sort CSR build (dense writes only).
// R9: all-bf16 dataflow + MFMA. Layer-2/3 GEMMs use mfma_f32_16x16x32_bf16
//     (A=rows bf16, B=W bf16 col-major via k_prep, f32 accum, al epilogue
//     in-register). f32 H/Y dataflow removed: gemms write only the bf16
//     table; k_agg writes bf16 Y for layers 1-2, f32 only for layer 3
//     (pool input). Fallback (deg>64) gathers bf16 table too.
// ---------------------------------------------------------------------------

#define BW 512          // nodes per bucket (power of 2)
#define PART_CHUNK 4096 // edges per WG in kb_part

typedef __attribute__((ext_vector_type(8))) short short8v;  // 8 bf16
typedef __attribute__((ext_vector_type(4))) float f32x4;

__device__ __forceinline__ float bflo(unsigned u) { return __uint_as_float(u << 16); }
__device__ __forceinline__ float bfhi(unsigned u) { return __uint_as_float(u & 0xffff0000u); }
// pack two f32 -> two bf16 (round-nearest-even), a in low half, b in high
__device__ __forceinline__ unsigned pk2bf(float a, float b) {
  unsigned ua = __float_as_uint(a); ua += 0x7fffu + ((ua >> 16) & 1u);
  unsigned ub = __float_as_uint(b); ub += 0x7fffu + ((ub >> 16) & 1u);
  return (ua >> 16) | (ub & 0xffff0000u);
}

// ---- CSR build, stage 1: per-bucket edge counts (LDS histogram) ----
__global__ __launch_bounds__(256) void kb_hist(const int* __restrict__ ei,
                                               int* __restrict__ bcnt,
                                               int E, int ET, int NB) {
  __shared__ int h[128];
  int tid = threadIdx.x;
  if (tid < 128) h[tid] = 0;
  __syncthreads();
  int stride = gridDim.x * 256;
  for (int i = blockIdx.x * 256 + tid; i < ET; i += stride) {
    int dst = (i < E) ? ei[E + i] : (i - E);
    atomicAdd(&h[dst >> 9], 1);
  }
  __syncthreads();
  if (tid < NB && h[tid] > 0) atomicAdd(&bcnt[tid], h[tid]);
}

// ---- stage 2: 1 WG exclusive-scans NB (<=128) bucket counts ----
__global__ __launch_bounds__(128) void kb_scan(const int* __restrict__ bcnt,
                                               int* __restrict__ bbase,
                                               int* __restrict__ bcur,
                                               int* __restrict__ rowp,
                                               int N, int ET, int NB) {
  __shared__ int sm[128];
  int t = threadIdx.x;
  int v = (t < NB) ? bcnt[t] : 0;
  sm[t] = v;
  __syncthreads();
  for (int off = 1; off < 128; off <<= 1) {
    int u = (t >= off) ? sm[t - off] : 0;
    __syncthreads();
    sm[t] += u;
    __syncthreads();
  }
  int pre = sm[t] - v;                  // exclusive
  if (t <= NB) bbase[t] = pre;          // bbase[NB] == ET
  if (t < NB) bcur[t] = pre;
  if (t == 0) rowp[N] = ET;
}

// ---- stage 3: partition edges into bucket runs (packed src<<9|dstlocal) ----
__global__ __launch_bounds__(256) void kb_part(const int* __restrict__ ei,
                                               int* __restrict__ bcur,
                                               int* __restrict__ bucketed,
                                               int E, int ET, int NB) {
  __shared__ int hist[128];
  __shared__ int runb[128];
  int tid = threadIdx.x;
  int base = blockIdx.x * PART_CHUNK;
  if (tid < 128) hist[tid] = 0;

  int sv[16], dv[16];
#pragma unroll
  for (int k = 0; k < 16; ++k) {
    int j = base + k * 256 + tid;
    int s = -1, d = 0;
    if (j < ET) {
      if (j < E) { s = ei[j]; d = ei[E + j]; }
      else       { s = j - E; d = j - E; }
    }
    sv[k] = s; dv[k] = d;
  }
  __syncthreads();
#pragma unroll
  for (int k = 0; k < 16; ++k)
    if (sv[k] >= 0) atomicAdd(&hist[dv[k] >> 9], 1);
  __syncthreads();
  if (tid < NB && hist[tid] > 0) runb[tid] = atomicAdd(&bcur[tid], hist[tid]);
  __syncthreads();
  if (tid < 128) hist[tid] = 0;   // reuse as within-run cursor
  __syncthreads();
#pragma unroll
  for (int k = 0; k < 16; ++k) {
    if (sv[k] >= 0) {
      int b = dv[k] >> 9;
      int off = atomicAdd(&hist[b], 1);
      bucketed[runb[b] + off] = (sv[k] << 9) | (dv[k] & (BW - 1));
    }
  }
}

// ---- stage 4: per-bucket counting sort -> rowp segment + csr window ----
__global__ __launch_bounds__(256) void kb_csr(const int* __restrict__ bucketed,
                                              const int* __restrict__ bbase,
                                              int* __restrict__ rowp,
                                              int* __restrict__ csr,
                                              int N) {
  __shared__ int h[512];
  __shared__ int sm[256];
  __shared__ int cur[512];
  int tid = threadIdx.x;
  int b = blockIdx.x;
  int cb = bbase[b], ce = bbase[b + 1];

  h[tid] = 0; h[tid + 256] = 0;
  __syncthreads();
  for (int j = cb + tid; j < ce; j += 256)
    atomicAdd(&h[bucketed[j] & (BW - 1)], 1);
  __syncthreads();
  int a0 = h[2 * tid], a1 = h[2 * tid + 1];
  int s = a0 + a1;
  sm[tid] = s;
  __syncthreads();
  for (int off = 1; off < 256; off <<= 1) {
    int u = (tid >= off) ? sm[tid - off] : 0;
    __syncthreads();
    sm[tid] += u;
    __syncthreads();
  }
  int pre = sm[tid] - s;                 // exclusive over pairs
  cur[2 * tid] = pre;
  cur[2 * tid + 1] = pre + a0;
  __syncthreads();
  int node0 = b * BW;
  for (int local = tid; local < BW; local += 256) {
    int node = node0 + local;
    if (node < N) rowp[node] = cb + cur[local];   // coalesced segment write
  }
  __syncthreads();
  for (int j = cb + tid; j < ce; j += 256) {
    int p = bucketed[j];
    int loc = p & (BW - 1);
    int pos = cb + atomicAdd(&cur[loc], 1);
    csr[pos] = (unsigned)p >> 9;          // confined to [cb,ce) window
  }
}

// ---- bf16 col-major W prep for the two 128x128 MFMA gemms ----
__global__ __launch_bounds__(256) void k_prep(const float* __restrict__ W2,
                                              const float* __restrict__ W3,
                                              unsigned short* __restrict__ Wcm2,
                                              unsigned short* __restrict__ Wcm3) {
  int i = blockIdx.x * 256 + threadIdx.x;   // 16384 = 128*128
  if (i < 16384) {
    int k = i >> 7, n = i & 127;
    unsigned u = __float_as_uint(W2[i]); u += 0x7fffu + ((u >> 16) & 1u);
    Wcm2[n * 128 + k] = (unsigned short)(u >> 16);
    unsigned v = __float_as_uint(W3[i]); v += 0x7fffu + ((v >> 16) & 1u);
    Wcm3[n * 128 + k] = (unsigned short)(v >> 16);
  }
}

// layer-1 GEMM fused with al: one wave per node, lane owns 2 features.
// Writes only the bf16 table + al.
__global__ __launch_bounds__(256) void k_gemm4al(const float* __restrict__ X,
                                                 const float* __restrict__ W,
                                                 const float* __restrict__ asv,
                                                 const float* __restrict__ adv,
                                                 unsigned* __restrict__ Hbf,
                                                 float* __restrict__ al_s,
                                                 float* __restrict__ al_d, int N) {
  int wid = threadIdx.x >> 6, lane = threadIdx.x & 63;
  int node = blockIdx.x * 4 + wid;
  if (node >= N) return;
  float4 xv = *(const float4*)(X + node * 4);
  int f = lane * 2;
  float2 w0 = *(const float2*)(W + f);
  float2 w1 = *(const float2*)(W + 128 + f);
  float2 w2 = *(const float2*)(W + 256 + f);
  float2 w3 = *(const float2*)(W + 384 + f);
  float h0 = xv.x * w0.x + xv.y * w1.x + xv.z * w2.x + xv.w * w3.x;
  float h1 = xv.x * w0.y + xv.y * w1.y + xv.z * w2.y + xv.w * w3.y;
  Hbf[node * 64 + lane] = pk2bf(h0, h1);
  float2 s2 = *(const float2*)(asv + f);
  float2 d2 = *(const float2*)(adv + f);
  float ps = h0 * s2.x + h1 * s2.y;
  float pd = h0 * d2.x + h1 * d2.y;
  for (int off = 32; off; off >>= 1) {
    ps += __shfl_xor(ps, off);
    pd += __shfl_xor(pd, off);
  }
  if (lane == 0) { al_s[node] = ps; al_d[node] = pd; }
}

// MFMA GEMM: Xbf [N,128] bf16 @ Wcm [128,128] bf16 (col-major) -> Hbf bf16,
// fused al epilogue. One wave per 16 rows; 8 col-frags x 4 k-tiles of
// mfma_f32_16x16x32_bf16. A: row=lane&15, k=(lane>>4)*8+i (16B global load).
// B: col=lane&15, same k slicing (16B from col-major W). C: col=lane&15,
// row=(lane>>4)*4+reg (verified layout). All shfls exec-uniform.
__global__ __launch_bounds__(256) void k_gemm128mfma(
    const unsigned short* __restrict__ Xbf,
    const unsigned short* __restrict__ Wcm,
    const float* __restrict__ asv, const float* __restrict__ adv,
    unsigned* __restrict__ Hbf,
    float* __restrict__ al_s, float* __restrict__ al_d, int N) {
  int wid = threadIdx.x >> 6, lane = threadIdx.x & 63;
  int c = lane & 15, g = lane >> 4;
  int row0 = blockIdx.x * 64 + wid * 16;
  int arow = row0 + c;
  int arowc = (arow < N) ? arow : (N - 1);

  short8v a[4];
#pragma unroll
  for (int kt = 0; kt < 4; ++kt)
    a[kt] = *(const short8v*)(Xbf + (size_t)arowc * 128 + kt * 32 + g * 8);

  f32x4 acc[8];
#pragma unroll
  for (int f = 0; f < 8; ++f) acc[f] = (f32x4){0.f, 0.f, 0.f, 0.f};

#pragma unroll
  for (int f = 0; f < 8; ++f) {
    const unsigned short* wb = Wcm + (size_t)(f * 16 + c) * 128 + g * 8;
#pragma unroll
    for (int kt = 0; kt < 4; ++kt) {
      short8v b = *(const short8v*)(wb + kt * 32);
      acc[f] = __builtin_amdgcn_mfma_f32_16x16x32_bf16(a[kt], b, acc[f], 0, 0, 0);
    }
  }

  // al epilogue: ps/pd per row, reduce across the 16 col-lanes
  float ps[4] = {0.f, 0.f, 0.f, 0.f}, pd[4] = {0.f, 0.f, 0.f, 0.f};
#pragma unroll
  for (int f = 0; f < 8; ++f) {
    float as_c = asv[f * 16 + c], ad_c = adv[f * 16 + c];
#pragma unroll
    for (int j = 0; j < 4; ++j) { ps[j] += acc[f][j] * as_c; pd[j] += acc[f][j] * ad_c; }
  }
#pragma unroll
  for (int j = 0; j < 4; ++j) {
    for (int off = 1; off < 16; off <<= 1) {
      ps[j] += __shfl_xor(ps[j], off);
      pd[j] += __shfl_xor(pd[j], off);
    }
  }
  if (c == 0) {
#pragma unroll
    for (int j = 0; j < 4; ++j) {
      int r = row0 + g * 4 + j;
      if (r < N) { al_s[r] = ps[j]; al_d[r] = pd[j]; }
    }
  }

  // bf16 store: pair adjacent cols via shfl (uniform exec), even lanes store u32
#pragma unroll
  for (int f = 0; f < 8; ++f) {
#pragma unroll
    for (int j = 0; j < 4; ++j) {
      float partner = __shfl_xor(acc[f][j], 1);
      int r = row0 + g * 4 + j;
      if (((lane & 1) == 0) && r < N)
        Hbf[(size_t)r * 64 + f * 8 + (c >> 1)] = pk2bf(acc[f][j], partner);
    }
  }
}

// per-dst softmax + aggregation. one wave per dst.
// Fast path (deg <= 64): lane owns one edge; softmax in registers;
//   gathers one uint4 (8 bf16) per lane per edge. Shfls exec-uniform.
// Fallback (deg > 64): 3-pass with per-edge scratch, bf16 gather.
// Output: relu!=0 -> bf16 Y (next gemm input); relu==0 -> f32 Y (pool).
__global__ __launch_bounds__(256) void k_agg(const int* __restrict__ csr_src,
                                             const int* __restrict__ rowp,
                                             const float* __restrict__ al_s,
                                             const float* __restrict__ al_d,
                                             const uint4* __restrict__ Hbf,
                                             const float* __restrict__ bias,
                                             float* __restrict__ exw,
                                             float* __restrict__ Yf32,
                                             uint4* __restrict__ Ybf,
                                             int N, int relu) {
  int wid = threadIdx.x >> 6, lane = threadIdx.x & 63;
  int dst = blockIdx.x * 4 + wid;
  if (dst >= N) return;
  int beg = rowp[dst], end = rowp[dst + 1];
  int deg = end - beg;
  float ald = al_d[dst];

  int q = lane >> 4;       // quarter = edge offset within 4-edge group
  int l = lane & 15;       // feature lane: owns feats [l*8, l*8+8)
  float acc[8];
#pragma unroll
  for (int c = 0; c < 8; ++c) acc[c] = 0.f;

  if (deg <= 64) {
    // ---- register-resident softmax ----
    int srcv = 0;
    float e = -INFINITY;
    if (lane < deg) {
      srcv = csr_src[beg + lane];
      e = al_s[srcv] + ald;
      e = (e > 0.f) ? e : 0.2f * e;
    }
    float m = e;
    for (int off = 32; off; off >>= 1) m = fmaxf(m, __shfl_xor(m, off));
    float av = (lane < deg) ? __expf(e - m) : 0.f;
    float den = av;
    for (int off = 32; off; off >>= 1) den += __shfl_xor(den, off);
    av *= 1.0f / (den + 1e-16f);   // alpha, pre-normalized, in lane=edge

    int t = 0;
    for (; t + 8 <= deg; t += 8) {     // deg uniform: wave-uniform loop
      int sA = __shfl(srcv, t + q);
      int sB = __shfl(srcv, t + 4 + q);
      float wA = __shfl(av, t + q);
      float wB = __shfl(av, t + 4 + q);
      uint4 va = Hbf[(size_t)sA * 16 + l];
      uint4 vb = Hbf[(size_t)sB * 16 + l];
      acc[0] += wA * bflo(va.x) + wB * bflo(vb.x);
      acc[1] += wA * bfhi(va.x) + wB * bfhi(vb.x);
      acc[2] += wA * bflo(va.y) + wB * bflo(vb.y);
      acc[3] += wA * bfhi(va.y) + wB * bfhi(vb.y);
      acc[4] += wA * bflo(va.z) + wB * bflo(vb.z);
      acc[5] += wA * bfhi(va.z) + wB * bfhi(vb.z);
      acc[6] += wA * bflo(va.w) + wB * bflo(vb.w);
      acc[7] += wA * bfhi(va.w) + wB * bfhi(vb.w);
    }
    if (t + 4 <= deg) {                // uniform guard
      int sA = __shfl(srcv, t + q);
      float wA = __shfl(av, t + q);
      uint4 va = Hbf[(size_t)sA * 16 + l];
      acc[0] += wA * bflo(va.x); acc[1] += wA * bfhi(va.x);
      acc[2] += wA * bflo(va.y); acc[3] += wA * bfhi(va.y);
      acc[4] += wA * bflo(va.z); acc[5] += wA * bfhi(va.z);
      acc[6] += wA * bflo(va.w); acc[7] += wA * bfhi(va.w);
      t += 4;
    }
    {
      // tail: shfls hoisted OUT of the divergent guard (uniform exec)
      int sA = __shfl(srcv, t + q);
      float wA = __shfl(av, t + q);
      if (t + q < deg) {               // divergent: memory ops only
        uint4 va = Hbf[(size_t)sA * 16 + l];
        acc[0] += wA * bflo(va.x); acc[1] += wA * bfhi(va.x);
        acc[2] += wA * bflo(va.y); acc[3] += wA * bfhi(va.y);
        acc[4] += wA * bflo(va.z); acc[5] += wA * bfhi(va.z);
        acc[6] += wA * bflo(va.w); acc[7] += wA * bfhi(va.w);
      }
    }
  } else {
    // ---- generic fallback: 3-pass with per-edge scratch (bf16 gather) ----
    float m = -INFINITY;
    for (int j = beg + lane; j < end; j += 64) {
      float e = al_s[csr_src[j]] + ald;
      e = (e > 0.f) ? e : 0.2f * e;
      exw[j] = e;
      m = fmaxf(m, e);
    }
    for (int off = 32; off; off >>= 1) m = fmaxf(m, __shfl_xor(m, off));

    float den = 0.f;
    for (int j = beg + lane; j < end; j += 64) {
      float ex = __expf(exw[j] - m);
      exw[j] = ex;
      den += ex;
    }
    for (int off = 32; off; off >>= 1) den += __shfl_xor(den, off);
    float inv = 1.0f / (den + 1e-16f);

    for (int j = beg + q; j < end; j += 4) {
      int sA = csr_src[j];
      float wA = exw[j] * inv;
      uint4 va = Hbf[(size_t)sA * 16 + l];
      acc[0] += wA * bflo(va.x); acc[1] += wA * bfhi(va.x);
      acc[2] += wA * bflo(va.y); acc[3] += wA * bfhi(va.y);
      acc[4] += wA * bflo(va.z); acc[5] += wA * bfhi(va.z);
      acc[6] += wA * bflo(va.w); acc[7] += wA * bfhi(va.w);
    }
  }

#pragma unroll
  for (int c = 0; c < 8; ++c) {
    acc[c] += __shfl_xor(acc[c], 16);
    acc[c] += __shfl_xor(acc[c], 32);
  }
  if (q == 0) {
    float4 bv0 = *(const float4*)(bias + l * 8);
    float4 bv1 = *(const float4*)(bias + l * 8 + 4);
    float o0 = acc[0] + bv0.x, o1 = acc[1] + bv0.y, o2 = acc[2] + bv0.z, o3 = acc[3] + bv0.w;
    float o4 = acc[4] + bv1.x, o5 = acc[5] + bv1.y, o6 = acc[6] + bv1.z, o7 = acc[7] + bv1.w;
    if (relu) {
      o0 = fmaxf(o0, 0.f); o1 = fmaxf(o1, 0.f); o2 = fmaxf(o2, 0.f); o3 = fmaxf(o3, 0.f);
      o4 = fmaxf(o4, 0.f); o5 = fmaxf(o5, 0.f); o6 = fmaxf(o6, 0.f); o7 = fmaxf(o7, 0.f);
      uint4 pb;
      pb.x = pk2bf(o0, o1); pb.y = pk2bf(o2, o3);
      pb.z = pk2bf(o4, o5); pb.w = pk2bf(o6, o7);
      Ybf[(size_t)dst * 16 + l] = pb;
    } else {
      float4 w0 = make_float4(o0, o1, o2, o3);
      float4 w1 = make_float4(o4, o5, o6, o7);
      *(float4*)(Yf32 + (size_t)dst * 128 + l * 8) = w0;
      *(float4*)(Yf32 + (size_t)dst * 128 + l * 8 + 4) = w1;
    }
  }
}

// run-length pooling over sorted batch
__global__ __launch_bounds__(256) void k_pool(const float* __restrict__ Hh,
                                              const int* __restrict__ batch,
                                              float* __restrict__ gsum,
                                              float* __restrict__ gcnt,
                                              int N, int nwaves) {
  int gw = (blockIdx.x * 256 + threadIdx.x) >> 6;
  int lane = threadIdx.x & 63;
  int chunk = (N + nwaves - 1) / nwaves;
  int beg = gw * chunk;
  int end = beg + chunk; if (end > N) end = N;
  if (beg >= end) return;

  int curg = batch[beg];
  float2 acc = {0.f, 0.f};
  int cnt = 0;
  for (int n = beg; n < end; ++n) {
    int g = batch[n];
    if (g != curg) {
      atomicAdd(&gsum[curg * 128 + lane * 2], acc.x);
      atomicAdd(&gsum[curg * 128 + lane * 2 + 1], acc.y);
      if (lane == 0) atomicAdd(&gcnt[curg], (float)cnt);
      acc.x = 0.f; acc.y = 0.f; cnt = 0; curg = g;
    }
    float2 h = *(const float2*)(Hh + (size_t)n * 128 + lane * 2);
    acc.x += h.x; acc.y += h.y; ++cnt;
  }
  atomicAdd(&gsum[curg * 128 + lane * 2], acc.x);
  atomicAdd(&gsum[curg * 128 + lane * 2 + 1], acc.y);
  if (lane == 0) atomicAdd(&gcnt[curg], (float)cnt);
}

__global__ __launch_bounds__(128) void k_final(const float* __restrict__ gsum,
                                               const float* __restrict__ gcnt,
                                               const float* __restrict__ Wlin,
                                               const float* __restrict__ blin,
                                               float* __restrict__ out) {
  int t = threadIdx.x;  // 128 threads: (g, c) pairs
  int g = t >> 1, c = t & 1;
  float inv = 1.0f / fmaxf(gcnt[g], 1.0f);
  float acc = blin[c];
  for (int k = 0; k < 128; ++k) acc += gsum[g * 128 + k] * inv * Wlin[k * 2 + c];
  out[g * 2 + c] = acc;
}

extern "C" void kernel_launch(void* const* d_in, const int* in_sizes, int n_in,
                              void* d_out, int out_size, void* d_ws, size_t ws_size,
                              hipStream_t stream) {
  const float* x    = (const float*)d_in[0];
  const int*   ei   = (const int*)d_in[1];
  const int*   batch= (const int*)d_in[2];
  const float* W1   = (const float*)d_in[3];
  const float* as1  = (const float*)d_in[4];
  const float* ad1  = (const float*)d_in[5];
  const float* b1   = (const float*)d_in[6];
  const float* W2   = (const float*)d_in[7];
  const float* as2  = (const float*)d_in[8];
  const float* ad2  = (const float*)d_in[9];
  const float* b2   = (const float*)d_in[10];
  const float* W3   = (const float*)d_in[11];
  const float* as3  = (const float*)d_in[12];
  const float* ad3  = (const float*)d_in[13];
  const float* b3   = (const float*)d_in[14];
  const float* Wlin = (const float*)d_in[15];
  const float* blin = (const float*)d_in[16];

  int N = in_sizes[0] / 4;
  int E = in_sizes[1] / 2;
  int ET = E + N;
  int NB = (N + BW - 1) / BW;   // buckets (<=128 for N<=65536)

  char* ws = (char*)d_ws;
  unsigned* bfA = (unsigned*)ws; ws += (size_t)N * 64 * 4;   // bf16 H table
  unsigned* bfB = (unsigned*)ws; ws += (size_t)N * 64 * 4;   // bf16 Y table
  float* bufY = (float*)ws; ws += (size_t)N * 128 * 4;       // f32 Y (layer 3)
  float* al_s = (float*)ws; ws += (size_t)N * 4;
  float* al_d = (float*)ws; ws += (size_t)N * 4;
  float* gsum = (float*)ws; ws += (size_t)64 * 128 * 4;
  float* gcnt = (float*)ws; ws += (size_t)64 * 4;
  int* rowp   = (int*)ws;   ws += (size_t)(N + 1) * 4;
  int* csr    = (int*)ws;   ws += (size_t)ET * 4;
  float* exw  = (float*)ws; ws += (size_t)ET * 4;
  int* bucketed = (int*)ws; ws += (size_t)ET * 4;
  int* bcnt   = (int*)ws;   ws += (size_t)128 * 4;
  int* bbase  = (int*)ws;   ws += (size_t)132 * 4;
  int* bcur   = (int*)ws;   ws += (size_t)128 * 4;
  unsigned short* wcm2 = (unsigned short*)ws; ws += (size_t)128 * 128 * 2;
  unsigned short* wcm3 = (unsigned short*)ws; ws += (size_t)128 * 128 * 2;

  hipMemsetAsync(bcnt, 0, (size_t)128 * 4, stream);
  hipMemsetAsync(gsum, 0, (size_t)(64 * 128 + 64) * 4, stream);  // gsum + gcnt

  // CSR build (bucketed counting sort) + W prep
  kb_hist<<<256, 256, 0, stream>>>(ei, bcnt, E, ET, NB);
  kb_scan<<<1, 128, 0, stream>>>(bcnt, bbase, bcur, rowp, N, ET, NB);
  kb_part<<<(ET + PART_CHUNK - 1) / PART_CHUNK, 256, 0, stream>>>(ei, bcur, bucketed, E, ET, NB);
  kb_csr <<<NB, 256, 0, stream>>>(bucketed, bbase, rowp, csr, N);
  k_prep <<<64, 256, 0, stream>>>(W2, W3, wcm2, wcm3);

  int nb4 = (N + 3) / 4;
  int nb64 = (N + 63) / 64;
  // layer 1
  k_gemm4al<<<nb4, 256, 0, stream>>>(x, W1, as1, ad1, bfA, al_s, al_d, N);
  k_agg    <<<nb4, 256, 0, stream>>>(csr, rowp, al_s, al_d, (const uint4*)bfA, b1, exw, bufY, (uint4*)bfB, N, 1);
  // layer 2
  k_gemm128mfma<<<nb64, 256, 0, stream>>>((const unsigned short*)bfB, wcm2, as2, ad2, bfA, al_s, al_d, N);
  k_agg        <<<nb4, 256, 0, stream>>>(csr, rowp, al_s, al_d, (const uint4*)bfA, b2, exw, bufY, (uint4*)bfB, N, 1);
  // layer 3
  k_gemm128mfma<<<nb64, 256, 0, stream>>>((const unsigned short*)bfB, wcm3, as3, ad3, bfA, al_s, al_d, N);
  k_agg        <<<nb4, 256, 0, stream>>>(csr, rowp, al_s, al_d, (const uint4*)bfA, b3, exw, bufY, (uint4*)bfB, N, 0);

  // global mean pool + linear head (256 blocks x 4 waves = 1024 waves)
  k_pool <<<256, 256, 0, stream>>>(bufY, batch, gsum, gcnt, N, 1024);
  k_final<<<1, 128, 0, stream>>>(gsum, gcnt, Wlin, blin, (float*)d_out);
}

// Round 6
// 330.729 us; speedup vs baseline: 1.4728x; 1.0490x over previous
//
#include <hip/hip_runtime.h>
#include <math.h>

// ---------------------------------------------------------------------------
// GAT 3-layer net. CSR by dst built once per call (bucketed counting sort).
// R1-R8: see history (register softmax, bf16 gather table, counting-sort CSR).
// R9: all-bf16 dataflow + MFMA for layers 2/3 (mfma_f32_16x16x32_bf16).
// R10: layer-1 algebraic restructure. Agg and linear map commute:
//      Y1 = relu((A @ X) @ W1 + b1), al1 = X @ (W1 @ a). Gather table becomes
//      X [N,4] f32 = 800 KB -> L2-resident on every XCD; layer-1's ~95MB
//      L2-miss gather collapses to ~14MB of L2 hits. k_al1/k_alnode/k_aggx/
//      k_gemm4b replace gemm4al+k_agg for layer 1. Also 16-edge unroll in
//      k_agg pass C (4 gather lines in flight per lane).
// ---------------------------------------------------------------------------

#define BW 512          // nodes per bucket (power of 2)
#define PART_CHUNK 4096 // edges per WG in kb_part

typedef __attribute__((ext_vector_type(8))) short short8v;  // 8 bf16
typedef __attribute__((ext_vector_type(4))) float f32x4;

__device__ __forceinline__ float bflo(unsigned u) { return __uint_as_float(u << 16); }
__device__ __forceinline__ float bfhi(unsigned u) { return __uint_as_float(u & 0xffff0000u); }
// pack two f32 -> two bf16 (round-nearest-even), a in low half, b in high
__device__ __forceinline__ unsigned pk2bf(float a, float b) {
  unsigned ua = __float_as_uint(a); ua += 0x7fffu + ((ua >> 16) & 1u);
  unsigned ub = __float_as_uint(b); ub += 0x7fffu + ((ub >> 16) & 1u);
  return (ua >> 16) | (ub & 0xffff0000u);
}

// ---- CSR build, stage 1: per-bucket edge counts (LDS histogram) ----
__global__ __launch_bounds__(256) void kb_hist(const int* __restrict__ ei,
                                               int* __restrict__ bcnt,
                                               int E, int ET, int NB) {
  __shared__ int h[128];
  int tid = threadIdx.x;
  if (tid < 128) h[tid] = 0;
  __syncthreads();
  int stride = gridDim.x * 256;
  for (int i = blockIdx.x * 256 + tid; i < ET; i += stride) {
    int dst = (i < E) ? ei[E + i] : (i - E);
    atomicAdd(&h[dst >> 9], 1);
  }
  __syncthreads();
  if (tid < NB && h[tid] > 0) atomicAdd(&bcnt[tid], h[tid]);
}

// ---- stage 2: 1 WG exclusive-scans NB (<=128) bucket counts ----
__global__ __launch_bounds__(128) void kb_scan(const int* __restrict__ bcnt,
                                               int* __restrict__ bbase,
                                               int* __restrict__ bcur,
                                               int* __restrict__ rowp,
                                               int N, int ET, int NB) {
  __shared__ int sm[128];
  int t = threadIdx.x;
  int v = (t < NB) ? bcnt[t] : 0;
  sm[t] = v;
  __syncthreads();
  for (int off = 1; off < 128; off <<= 1) {
    int u = (t >= off) ? sm[t - off] : 0;
    __syncthreads();
    sm[t] += u;
    __syncthreads();
  }
  int pre = sm[t] - v;                  // exclusive
  if (t <= NB) bbase[t] = pre;          // bbase[NB] == ET
  if (t < NB) bcur[t] = pre;
  if (t == 0) rowp[N] = ET;
}

// ---- stage 3: partition edges into bucket runs (packed src<<9|dstlocal) ----
__global__ __launch_bounds__(256) void kb_part(const int* __restrict__ ei,
                                               int* __restrict__ bcur,
                                               int* __restrict__ bucketed,
                                               int E, int ET, int NB) {
  __shared__ int hist[128];
  __shared__ int runb[128];
  int tid = threadIdx.x;
  int base = blockIdx.x * PART_CHUNK;
  if (tid < 128) hist[tid] = 0;

  int sv[16], dv[16];
#pragma unroll
  for (int k = 0; k < 16; ++k) {
    int j = base + k * 256 + tid;
    int s = -1, d = 0;
    if (j < ET) {
      if (j < E) { s = ei[j]; d = ei[E + j]; }
      else       { s = j - E; d = j - E; }
    }
    sv[k] = s; dv[k] = d;
  }
  __syncthreads();
#pragma unroll
  for (int k = 0; k < 16; ++k)
    if (sv[k] >= 0) atomicAdd(&hist[dv[k] >> 9], 1);
  __syncthreads();
  if (tid < NB && hist[tid] > 0) runb[tid] = atomicAdd(&bcur[tid], hist[tid]);
  __syncthreads();
  if (tid < 128) hist[tid] = 0;   // reuse as within-run cursor
  __syncthreads();
#pragma unroll
  for (int k = 0; k < 16; ++k) {
    if (sv[k] >= 0) {
      int b = dv[k] >> 9;
      int off = atomicAdd(&hist[b], 1);
      bucketed[runb[b] + off] = (sv[k] << 9) | (dv[k] & (BW - 1));
    }
  }
}

// ---- stage 4: per-bucket counting sort -> rowp segment + csr window ----
__global__ __launch_bounds__(256) void kb_csr(const int* __restrict__ bucketed,
                                              const int* __restrict__ bbase,
                                              int* __restrict__ rowp,
                                              int* __restrict__ csr,
                                              int N) {
  __shared__ int h[512];
  __shared__ int sm[256];
  __shared__ int cur[512];
  int tid = threadIdx.x;
  int b = blockIdx.x;
  int cb = bbase[b], ce = bbase[b + 1];

  h[tid] = 0; h[tid + 256] = 0;
  __syncthreads();
  for (int j = cb + tid; j < ce; j += 256)
    atomicAdd(&h[bucketed[j] & (BW - 1)], 1);
  __syncthreads();
  int a0 = h[2 * tid], a1 = h[2 * tid + 1];
  int s = a0 + a1;
  sm[tid] = s;
  __syncthreads();
  for (int off = 1; off < 256; off <<= 1) {
    int u = (tid >= off) ? sm[tid - off] : 0;
    __syncthreads();
    sm[tid] += u;
    __syncthreads();
  }
  int pre = sm[tid] - s;                 // exclusive over pairs
  cur[2 * tid] = pre;
  cur[2 * tid + 1] = pre + a0;
  __syncthreads();
  int node0 = b * BW;
  for (int local = tid; local < BW; local += 256) {
    int node = node0 + local;
    if (node < N) rowp[node] = cb + cur[local];   // coalesced segment write
  }
  __syncthreads();
  for (int j = cb + tid; j < ce; j += 256) {
    int p = bucketed[j];
    int loc = p & (BW - 1);
    int pos = cb + atomicAdd(&cur[loc], 1);
    csr[pos] = (unsigned)p >> 9;          // confined to [cb,ce) window
  }
}

// ---- bf16 col-major W prep for the two 128x128 MFMA gemms ----
__global__ __launch_bounds__(256) void k_prep(const float* __restrict__ W2,
                                              const float* __restrict__ W3,
                                              unsigned short* __restrict__ Wcm2,
                                              unsigned short* __restrict__ Wcm3) {
  int i = blockIdx.x * 256 + threadIdx.x;   // 16384 = 128*128
  if (i < 16384) {
    int k = i >> 7, n = i & 127;
    unsigned u = __float_as_uint(W2[i]); u += 0x7fffu + ((u >> 16) & 1u);
    Wcm2[n * 128 + k] = (unsigned short)(u >> 16);
    unsigned v = __float_as_uint(W3[i]); v += 0x7fffu + ((v >> 16) & 1u);
    Wcm3[n * 128 + k] = (unsigned short)(v >> 16);
  }
}

// ---- layer-1 al vectors: wv[0..3] = W1@as1, wv[4..7] = W1@ad1 ----
__global__ __launch_bounds__(64) void k_al1(const float* __restrict__ W1,
                                            const float* __restrict__ as1,
                                            const float* __restrict__ ad1,
                                            float* __restrict__ wv) {
  int lane = threadIdx.x;   // 64 lanes, lane owns cols 2l,2l+1
  float2 a = *(const float2*)(as1 + lane * 2);
  float2 d = *(const float2*)(ad1 + lane * 2);
  float ps[4], pd[4];
#pragma unroll
  for (int k = 0; k < 4; ++k) {
    float2 w = *(const float2*)(W1 + k * 128 + lane * 2);
    ps[k] = w.x * a.x + w.y * a.y;
    pd[k] = w.x * d.x + w.y * d.y;
  }
  for (int off = 32; off; off >>= 1) {
#pragma unroll
    for (int k = 0; k < 4; ++k) {
      ps[k] += __shfl_xor(ps[k], off);
      pd[k] += __shfl_xor(pd[k], off);
    }
  }
  if (lane == 0) {
#pragma unroll
    for (int k = 0; k < 4; ++k) { wv[k] = ps[k]; wv[4 + k] = pd[k]; }
  }
}

// ---- layer-1 per-node al: al_s = x . wv[0..3], al_d = x . wv[4..7] ----
__global__ __launch_bounds__(256) void k_alnode(const float* __restrict__ X,
                                                const float* __restrict__ wv,
                                                float* __restrict__ al_s,
                                                float* __restrict__ al_d, int N) {
  int i = blockIdx.x * 256 + threadIdx.x;
  if (i >= N) return;
  float4 xv = *(const float4*)(X + i * 4);
  al_s[i] = xv.x * wv[0] + xv.y * wv[1] + xv.z * wv[2] + xv.w * wv[3];
  al_d[i] = xv.x * wv[4] + xv.y * wv[5] + xv.z * wv[6] + xv.w * wv[7];
}

// ---- layer-1 aggregation over raw X (16B rows, L2-resident table) ----
// one wave per dst; lane-per-edge softmax; each lane holds its edge's full
// x row; full-wave shfl reduce of alpha*x. Fallback (deg>64): strided.
__global__ __launch_bounds__(256) void k_aggx(const int* __restrict__ csr_src,
                                              const int* __restrict__ rowp,
                                              const float* __restrict__ al_s,
                                              const float* __restrict__ al_d,
                                              const float* __restrict__ X,
                                              float* __restrict__ exw,
                                              float* __restrict__ AX, int N) {
  int wid = threadIdx.x >> 6, lane = threadIdx.x & 63;
  int dst = blockIdx.x * 4 + wid;
  if (dst >= N) return;
  int beg = rowp[dst], end = rowp[dst + 1];
  int deg = end - beg;
  float ald = al_d[dst];
  float4 acc = {0.f, 0.f, 0.f, 0.f};

  if (deg <= 64) {
    int srcv = 0;
    float e = -INFINITY;
    if (lane < deg) {
      srcv = csr_src[beg + lane];
      e = al_s[srcv] + ald;
      e = (e > 0.f) ? e : 0.2f * e;
    }
    float m = e;
    for (int off = 32; off; off >>= 1) m = fmaxf(m, __shfl_xor(m, off));
    float av = (lane < deg) ? __expf(e - m) : 0.f;
    float den = av;
    for (int off = 32; off; off >>= 1) den += __shfl_xor(den, off);
    av *= 1.0f / (den + 1e-16f);
    float4 xv = {0.f, 0.f, 0.f, 0.f};
    if (lane < deg) xv = *(const float4*)(X + (size_t)srcv * 4);
    acc.x = av * xv.x; acc.y = av * xv.y; acc.z = av * xv.z; acc.w = av * xv.w;
  } else {
    float m = -INFINITY;
    for (int j = beg + lane; j < end; j += 64) {
      float e = al_s[csr_src[j]] + ald;
      e = (e > 0.f) ? e : 0.2f * e;
      exw[j] = e;
      m = fmaxf(m, e);
    }
    for (int off = 32; off; off >>= 1) m = fmaxf(m, __shfl_xor(m, off));
    float den = 0.f;
    for (int j = beg + lane; j < end; j += 64) {
      float ex = __expf(exw[j] - m);
      exw[j] = ex;
      den += ex;
    }
    for (int off = 32; off; off >>= 1) den += __shfl_xor(den, off);
    float inv = 1.0f / (den + 1e-16f);
    for (int j = beg + lane; j < end; j += 64) {
      int s = csr_src[j];
      float w = exw[j] * inv;
      float4 xv = *(const float4*)(X + (size_t)s * 4);
      acc.x += w * xv.x; acc.y += w * xv.y; acc.z += w * xv.z; acc.w += w * xv.w;
    }
  }
  for (int off = 32; off; off >>= 1) {
    acc.x += __shfl_xor(acc.x, off);
    acc.y += __shfl_xor(acc.y, off);
    acc.z += __shfl_xor(acc.z, off);
    acc.w += __shfl_xor(acc.w, off);
  }
  if (lane == 0) *(float4*)(AX + (size_t)dst * 4) = acc;
}

// ---- layer-1 tail gemm: Y1 = relu(AX @ W1 + b1) -> bf16 table ----
__global__ __launch_bounds__(256) void k_gemm4b(const float* __restrict__ AX,
                                                const float* __restrict__ W,
                                                const float* __restrict__ bias,
                                                unsigned* __restrict__ Ybf, int N) {
  int wid = threadIdx.x >> 6, lane = threadIdx.x & 63;
  int node = blockIdx.x * 4 + wid;
  if (node >= N) return;
  float4 xv = *(const float4*)(AX + (size_t)node * 4);
  int f = lane * 2;
  float2 w0 = *(const float2*)(W + f);
  float2 w1 = *(const float2*)(W + 128 + f);
  float2 w2 = *(const float2*)(W + 256 + f);
  float2 w3 = *(const float2*)(W + 384 + f);
  float2 bv = *(const float2*)(bias + f);
  float h0 = xv.x * w0.x + xv.y * w1.x + xv.z * w2.x + xv.w * w3.x + bv.x;
  float h1 = xv.x * w0.y + xv.y * w1.y + xv.z * w2.y + xv.w * w3.y + bv.y;
  h0 = fmaxf(h0, 0.f); h1 = fmaxf(h1, 0.f);
  Ybf[(size_t)node * 64 + lane] = pk2bf(h0, h1);
}

// MFMA GEMM: Xbf [N,128] bf16 @ Wcm [128,128] bf16 (col-major) -> Hbf bf16,
// fused al epilogue. One wave per 16 rows; 8 col-frags x 4 k-tiles of
// mfma_f32_16x16x32_bf16. C layout: col=lane&15, row=(lane>>4)*4+reg.
__global__ __launch_bounds__(256) void k_gemm128mfma(
    const unsigned short* __restrict__ Xbf,
    const unsigned short* __restrict__ Wcm,
    const float* __restrict__ asv, const float* __restrict__ adv,
    unsigned* __restrict__ Hbf,
    float* __restrict__ al_s, float* __restrict__ al_d, int N) {
  int wid = threadIdx.x >> 6, lane = threadIdx.x & 63;
  int c = lane & 15, g = lane >> 4;
  int row0 = blockIdx.x * 64 + wid * 16;
  int arow = row0 + c;
  int arowc = (arow < N) ? arow : (N - 1);

  short8v a[4];
#pragma unroll
  for (int kt = 0; kt < 4; ++kt)
    a[kt] = *(const short8v*)(Xbf + (size_t)arowc * 128 + kt * 32 + g * 8);

  f32x4 acc[8];
#pragma unroll
  for (int f = 0; f < 8; ++f) acc[f] = (f32x4){0.f, 0.f, 0.f, 0.f};

#pragma unroll
  for (int f = 0; f < 8; ++f) {
    const unsigned short* wb = Wcm + (size_t)(f * 16 + c) * 128 + g * 8;
#pragma unroll
    for (int kt = 0; kt < 4; ++kt) {
      short8v b = *(const short8v*)(wb + kt * 32);
      acc[f] = __builtin_amdgcn_mfma_f32_16x16x32_bf16(a[kt], b, acc[f], 0, 0, 0);
    }
  }

  // al epilogue: ps/pd per row, reduce across the 16 col-lanes
  float ps[4] = {0.f, 0.f, 0.f, 0.f}, pd[4] = {0.f, 0.f, 0.f, 0.f};
#pragma unroll
  for (int f = 0; f < 8; ++f) {
    float as_c = asv[f * 16 + c], ad_c = adv[f * 16 + c];
#pragma unroll
    for (int j = 0; j < 4; ++j) { ps[j] += acc[f][j] * as_c; pd[j] += acc[f][j] * ad_c; }
  }
#pragma unroll
  for (int j = 0; j < 4; ++j) {
    for (int off = 1; off < 16; off <<= 1) {
      ps[j] += __shfl_xor(ps[j], off);
      pd[j] += __shfl_xor(pd[j], off);
    }
  }
  if (c == 0) {
#pragma unroll
    for (int j = 0; j < 4; ++j) {
      int r = row0 + g * 4 + j;
      if (r < N) { al_s[r] = ps[j]; al_d[r] = pd[j]; }
    }
  }

  // bf16 store: pair adjacent cols via shfl (uniform exec), even lanes store u32
#pragma unroll
  for (int f = 0; f < 8; ++f) {
#pragma unroll
    for (int j = 0; j < 4; ++j) {
      float partner = __shfl_xor(acc[f][j], 1);
      int r = row0 + g * 4 + j;
      if (((lane & 1) == 0) && r < N)
        Hbf[(size_t)r * 64 + f * 8 + (c >> 1)] = pk2bf(acc[f][j], partner);
    }
  }
}

// per-dst softmax + aggregation. one wave per dst.
// Fast path (deg <= 64): lane owns one edge; softmax in registers;
//   gathers one uint4 (8 bf16) per lane per edge; 16-edge unroll (4 lines
//   in flight). Shfls exec-uniform. Fallback (deg > 64): 3-pass scratch.
// Output: relu!=0 -> bf16 Y (next gemm input); relu==0 -> f32 Y (pool).
__global__ __launch_bounds__(256) void k_agg(const int* __restrict__ csr_src,
                                             const int* __restrict__ rowp,
                                             const float* __restrict__ al_s,
                                             const float* __restrict__ al_d,
                                             const uint4* __restrict__ Hbf,
                                             const float* __restrict__ bias,
                                             float* __restrict__ exw,
                                             float* __restrict__ Yf32,
                                             uint4* __restrict__ Ybf,
                                             int N, int relu) {
  int wid = threadIdx.x >> 6, lane = threadIdx.x & 63;
  int dst = blockIdx.x * 4 + wid;
  if (dst >= N) return;
  int beg = rowp[dst], end = rowp[dst + 1];
  int deg = end - beg;
  float ald = al_d[dst];

  int q = lane >> 4;       // quarter = edge offset within 4-edge group
  int l = lane & 15;       // feature lane: owns feats [l*8, l*8+8)
  float acc[8];
#pragma unroll
  for (int c = 0; c < 8; ++c) acc[c] = 0.f;

  if (deg <= 64) {
    // ---- register-resident softmax ----
    int srcv = 0;
    float e = -INFINITY;
    if (lane < deg) {
      srcv = csr_src[beg + lane];
      e = al_s[srcv] + ald;
      e = (e > 0.f) ? e : 0.2f * e;
    }
    float m = e;
    for (int off = 32; off; off >>= 1) m = fmaxf(m, __shfl_xor(m, off));
    float av = (lane < deg) ? __expf(e - m) : 0.f;
    float den = av;
    for (int off = 32; off; off >>= 1) den += __shfl_xor(den, off);
    av *= 1.0f / (den + 1e-16f);   // alpha, pre-normalized, in lane=edge

    int t = 0;
    for (; t + 16 <= deg; t += 16) {   // 16-edge unroll: 4 lines in flight
      int s0 = __shfl(srcv, t + q);
      int s1 = __shfl(srcv, t + 4 + q);
      int s2 = __shfl(srcv, t + 8 + q);
      int s3 = __shfl(srcv, t + 12 + q);
      float w0 = __shfl(av, t + q);
      float w1 = __shfl(av, t + 4 + q);
      float w2 = __shfl(av, t + 8 + q);
      float w3 = __shfl(av, t + 12 + q);
      uint4 v0 = Hbf[(size_t)s0 * 16 + l];
      uint4 v1 = Hbf[(size_t)s1 * 16 + l];
      uint4 v2 = Hbf[(size_t)s2 * 16 + l];
      uint4 v3 = Hbf[(size_t)s3 * 16 + l];
      acc[0] += w0 * bflo(v0.x) + w1 * bflo(v1.x) + w2 * bflo(v2.x) + w3 * bflo(v3.x);
      acc[1] += w0 * bfhi(v0.x) + w1 * bfhi(v1.x) + w2 * bfhi(v2.x) + w3 * bfhi(v3.x);
      acc[2] += w0 * bflo(v0.y) + w1 * bflo(v1.y) + w2 * bflo(v2.y) + w3 * bflo(v3.y);
      acc[3] += w0 * bfhi(v0.y) + w1 * bfhi(v1.y) + w2 * bfhi(v2.y) + w3 * bfhi(v3.y);
      acc[4] += w0 * bflo(v0.z) + w1 * bflo(v1.z) + w2 * bflo(v2.z) + w3 * bflo(v3.z);
      acc[5] += w0 * bfhi(v0.z) + w1 * bfhi(v1.z) + w2 * bfhi(v2.z) + w3 * bfhi(v3.z);
      acc[6] += w0 * bflo(v0.w) + w1 * bflo(v1.w) + w2 * bflo(v2.w) + w3 * bflo(v3.w);
      acc[7] += w0 * bfhi(v0.w) + w1 * bfhi(v1.w) + w2 * bfhi(v2.w) + w3 * bfhi(v3.w);
    }
    if (t + 8 <= deg) {
      int sA = __shfl(srcv, t + q);
      int sB = __shfl(srcv, t + 4 + q);
      float wA = __shfl(av, t + q);
      float wB = __shfl(av, t + 4 + q);
      uint4 va = Hbf[(size_t)sA * 16 + l];
      uint4 vb = Hbf[(size_t)sB * 16 + l];
      acc[0] += wA * bflo(va.x) + wB * bflo(vb.x);
      acc[1] += wA * bfhi(va.x) + wB * bfhi(vb.x);
      acc[2] += wA * bflo(va.y) + wB * bflo(vb.y);
      acc[3] += wA * bfhi(va.y) + wB * bfhi(vb.y);
      acc[4] += wA * bflo(va.z) + wB * bflo(vb.z);
      acc[5] += wA * bfhi(va.z) + wB * bfhi(vb.z);
      acc[6] += wA * bflo(va.w) + wB * bflo(vb.w);
      acc[7] += wA * bfhi(va.w) + wB * bfhi(vb.w);
      t += 8;
    }
    if (t + 4 <= deg) {                // uniform guard
      int sA = __shfl(srcv, t + q);
      float wA = __shfl(av, t + q);
      uint4 va = Hbf[(size_t)sA * 16 + l];
      acc[0] += wA * bflo(va.x); acc[1] += wA * bfhi(va.x);
      acc[2] += wA * bflo(va.y); acc[3] += wA * bfhi(va.y);
      acc[4] += wA * bflo(va.z); acc[5] += wA * bfhi(va.z);
      acc[6] += wA * bflo(va.w); acc[7] += wA * bfhi(va.w);
      t += 4;
    }
    {
      // tail: shfls hoisted OUT of the divergent guard (uniform exec)
      int sA = __shfl(srcv, t + q);
      float wA = __shfl(av, t + q);
      if (t + q < deg) {               // divergent: memory ops only
        uint4 va = Hbf[(size_t)sA * 16 + l];
        acc[0] += wA * bflo(va.x); acc[1] += wA * bfhi(va.x);
        acc[2] += wA * bflo(va.y); acc[3] += wA * bfhi(va.y);
        acc[4] += wA * bflo(va.z); acc[5] += wA * bfhi(va.z);
        acc[6] += wA * bflo(va.w); acc[7] += wA * bfhi(va.w);
      }
    }
  } else {
    // ---- generic fallback: 3-pass with per-edge scratch (bf16 gather) ----
    float m = -INFINITY;
    for (int j = beg + lane; j < end; j += 64) {
      float e = al_s[csr_src[j]] + ald;
      e = (e > 0.f) ? e : 0.2f * e;
      exw[j] = e;
      m = fmaxf(m, e);
    }
    for (int off = 32; off; off >>= 1) m = fmaxf(m, __shfl_xor(m, off));

    float den = 0.f;
    for (int j = beg + lane; j < end; j += 64) {
      float ex = __expf(exw[j] - m);
      exw[j] = ex;
      den += ex;
    }
    for (int off = 32; off; off >>= 1) den += __shfl_xor(den, off);
    float inv = 1.0f / (den + 1e-16f);

    for (int j = beg + q; j < end; j += 4) {
      int sA = csr_src[j];
      float wA = exw[j] * inv;
      uint4 va = Hbf[(size_t)sA * 16 + l];
      acc[0] += wA * bflo(va.x); acc[1] += wA * bfhi(va.x);
      acc[2] += wA * bflo(va.y); acc[3] += wA * bfhi(va.y);
      acc[4] += wA * bflo(va.z); acc[5] += wA * bfhi(va.z);
      acc[6] += wA * bflo(va.w); acc[7] += wA * bfhi(va.w);
    }
  }

#pragma unroll
  for (int c = 0; c < 8; ++c) {
    acc[c] += __shfl_xor(acc[c], 16);
    acc[c] += __shfl_xor(acc[c], 32);
  }
  if (q == 0) {
    float4 bv0 = *(const float4*)(bias + l * 8);
    float4 bv1 = *(const float4*)(bias + l * 8 + 4);
    float o0 = acc[0] + bv0.x, o1 = acc[1] + bv0.y, o2 = acc[2] + bv0.z, o3 = acc[3] + bv0.w;
    float o4 = acc[4] + bv1.x, o5 = acc[5] + bv1.y, o6 = acc[6] + bv1.z, o7 = acc[7] + bv1.w;
    if (relu) {
      o0 = fmaxf(o0, 0.f); o1 = fmaxf(o1, 0.f); o2 = fmaxf(o2, 0.f); o3 = fmaxf(o3, 0.f);
      o4 = fmaxf(o4, 0.f); o5 = fmaxf(o5, 0.f); o6 = fmaxf(o6, 0.f); o7 = fmaxf(o7, 0.f);
      uint4 pb;
      pb.x = pk2bf(o0, o1); pb.y = pk2bf(o2, o3);
      pb.z = pk2bf(o4, o5); pb.w = pk2bf(o6, o7);
      Ybf[(size_t)dst * 16 + l] = pb;
    } else {
      float4 w0 = make_float4(o0, o1, o2, o3);
      float4 w1 = make_float4(o4, o5, o6, o7);
      *(float4*)(Yf32 + (size_t)dst * 128 + l * 8) = w0;
      *(float4*)(Yf32 + (size_t)dst * 128 + l * 8 + 4) = w1;
    }
  }
}

// run-length pooling over sorted batch
__global__ __launch_bounds__(256) void k_pool(const float* __restrict__ Hh,
                                              const int* __restrict__ batch,
                                              float* __restrict__ gsum,
                                              float* __restrict__ gcnt,
                                              int N, int nwaves) {
  int gw = (blockIdx.x * 256 + threadIdx.x) >> 6;
  int lane = threadIdx.x & 63;
  int chunk = (N + nwaves - 1) / nwaves;
  int beg = gw * chunk;
  int end = beg + chunk; if (end > N) end = N;
  if (beg >= end) return;

  int curg = batch[beg];
  float2 acc = {0.f, 0.f};
  int cnt = 0;
  for (int n = beg; n < end; ++n) {
    int g = batch[n];
    if (g != curg) {
      atomicAdd(&gsum[curg * 128 + lane * 2], acc.x);
      atomicAdd(&gsum[curg * 128 + lane * 2 + 1], acc.y);
      if (lane == 0) atomicAdd(&gcnt[curg], (float)cnt);
      acc.x = 0.f; acc.y = 0.f; cnt = 0; curg = g;
    }
    float2 h = *(const float2*)(Hh + (size_t)n * 128 + lane * 2);
    acc.x += h.x; acc.y += h.y; ++cnt;
  }
  atomicAdd(&gsum[curg * 128 + lane * 2], acc.x);
  atomicAdd(&gsum[curg * 128 + lane * 2 + 1], acc.y);
  if (lane == 0) atomicAdd(&gcnt[curg], (float)cnt);
}

__global__ __launch_bounds__(128) void k_final(const float* __restrict__ gsum,
                                               const float* __restrict__ gcnt,
                                               const float* __restrict__ Wlin,
                                               const float* __restrict__ blin,
                                               float* __restrict__ out) {
  int t = threadIdx.x;  // 128 threads: (g, c) pairs
  int g = t >> 1, c = t & 1;
  float inv = 1.0f / fmaxf(gcnt[g], 1.0f);
  float acc = blin[c];
  for (int k = 0; k < 128; ++k) acc += gsum[g * 128 + k] * inv * Wlin[k * 2 + c];
  out[g * 2 + c] = acc;
}

extern "C" void kernel_launch(void* const* d_in, const int* in_sizes, int n_in,
                              void* d_out, int out_size, void* d_ws, size_t ws_size,
                              hipStream_t stream) {
  const float* x    = (const float*)d_in[0];
  const int*   ei   = (const int*)d_in[1];
  const int*   batch= (const int*)d_in[2];
  const float* W1   = (const float*)d_in[3];
  const float* as1  = (const float*)d_in[4];
  const float* ad1  = (const float*)d_in[5];
  const float* b1   = (const float*)d_in[6];
  const float* W2   = (const float*)d_in[7];
  const float* as2  = (const float*)d_in[8];
  const float* ad2  = (const float*)d_in[9];
  const float* b2   = (const float*)d_in[10];
  const float* W3   = (const float*)d_in[11];
  const float* as3  = (const float*)d_in[12];
  const float* ad3  = (const float*)d_in[13];
  const float* b3   = (const float*)d_in[14];
  const float* Wlin = (const float*)d_in[15];
  const float* blin = (const float*)d_in[16];

  int N = in_sizes[0] / 4;
  int E = in_sizes[1] / 2;
  int ET = E + N;
  int NB = (N + BW - 1) / BW;   // buckets (<=128 for N<=65536)

  char* ws = (char*)d_ws;
  unsigned* bfA = (unsigned*)ws; ws += (size_t)N * 64 * 4;   // bf16 H table
  unsigned* bfB = (unsigned*)ws; ws += (size_t)N * 64 * 4;   // bf16 Y table
  float* bufY = (float*)ws; ws += (size_t)N * 128 * 4;       // f32 Y (layer 3)
  float* al_s = (float*)ws; ws += (size_t)N * 4;
  float* al_d = (float*)ws; ws += (size_t)N * 4;
  float* AX   = (float*)ws; ws += (size_t)N * 4 * 4;         // layer-1 agg out
  float* gsum = (float*)ws; ws += (size_t)64 * 128 * 4;
  float* gcnt = (float*)ws; ws += (size_t)64 * 4;
  float* wv   = (float*)ws; ws += (size_t)64 * 4;            // layer-1 al vecs
  int* rowp   = (int*)ws;   ws += (size_t)(N + 1) * 4;
  int* csr    = (int*)ws;   ws += (size_t)ET * 4;
  float* exw  = (float*)ws; ws += (size_t)ET * 4;
  int* bucketed = (int*)ws; ws += (size_t)ET * 4;
  int* bcnt   = (int*)ws;   ws += (size_t)128 * 4;
  int* bbase  = (int*)ws;   ws += (size_t)132 * 4;
  int* bcur   = (int*)ws;   ws += (size_t)128 * 4;
  unsigned short* wcm2 = (unsigned short*)ws; ws += (size_t)128 * 128 * 2;
  unsigned short* wcm3 = (unsigned short*)ws; ws += (size_t)128 * 128 * 2;

  hipMemsetAsync(bcnt, 0, (size_t)128 * 4, stream);
  hipMemsetAsync(gsum, 0, (size_t)(64 * 128 + 64) * 4, stream);  // gsum + gcnt

  // CSR build (bucketed counting sort) + W prep + layer-1 al vectors
  kb_hist<<<256, 256, 0, stream>>>(ei, bcnt, E, ET, NB);
  kb_scan<<<1, 128, 0, stream>>>(bcnt, bbase, bcur, rowp, N, ET, NB);
  kb_part<<<(ET + PART_CHUNK - 1) / PART_CHUNK, 256, 0, stream>>>(ei, bcur, bucketed, E, ET, NB);
  kb_csr <<<NB, 256, 0, stream>>>(bucketed, bbase, rowp, csr, N);
  k_prep <<<64, 256, 0, stream>>>(W2, W3, wcm2, wcm3);
  k_al1  <<<1, 64, 0, stream>>>(W1, as1, ad1, wv);

  int nb4 = (N + 3) / 4;
  int nb64 = (N + 63) / 64;
  // layer 1: al from X dots; gather X (L2-resident); tail gemm
  k_alnode<<<(N + 255) / 256, 256, 0, stream>>>(x, wv, al_s, al_d, N);
  k_aggx  <<<nb4, 256, 0, stream>>>(csr, rowp, al_s, al_d, x, exw, AX, N);
  k_gemm4b<<<nb4, 256, 0, stream>>>(AX, W1, b1, bfB, N);
  // layer 2
  k_gemm128mfma<<<nb64, 256, 0, stream>>>((const unsigned short*)bfB, wcm2, as2, ad2, bfA, al_s, al_d, N);
  k_agg        <<<nb4, 256, 0, stream>>>(csr, rowp, al_s, al_d, (const uint4*)bfA, b2, exw, bufY, (uint4*)bfB, N, 1);
  // layer 3
  k_gemm128mfma<<<nb64, 256, 0, stream>>>((const unsigned short*)bfB, wcm3, as3, ad3, bfA, al_s, al_d, N);
  k_agg        <<<nb4, 256, 0, stream>>>(csr, rowp, al_s, al_d, (const uint4*)bfA, b3, exw, bufY, (uint4*)bfB, N, 0);

  // global mean pool + linear head (256 blocks x 4 waves = 1024 waves)
  k_pool <<<256, 256, 0, stream>>>(bufY, batch, gsum, gcnt, N, 1024);
  k_final<<<1, 128, 0, stream>>>(gsum, gcnt, Wlin, blin, (float*)d_out);
}